// Round 1
// baseline (463.540 us; speedup 1.0000x reference)
//
#include <hip/hip_runtime.h>

typedef __attribute__((ext_vector_type(8))) short  short8;
typedef __attribute__((ext_vector_type(4))) float  f32x4;
typedef __attribute__((ext_vector_type(4))) unsigned int uint4v;
typedef __attribute__((ext_vector_type(2))) unsigned int uint2v;

#define NEG_INF (-3.402823466e38f)

__device__ __forceinline__ unsigned short bfbits(float f) {
    unsigned u = __builtin_bit_cast(unsigned, f);
    u += 0x7fffu + ((u >> 16) & 1u);
    return (unsigned short)(u >> 16);
}
__device__ __forceinline__ unsigned pk_bf16(float lo, float hi) {
    return (unsigned)bfbits(lo) | ((unsigned)bfbits(hi) << 16);
}
__device__ __forceinline__ float lofp(unsigned u) {
    return __builtin_bit_cast(float, u << 16);
}
__device__ __forceinline__ float hifp(unsigned u) {
    return __builtin_bit_cast(float, u & 0xffff0000u);
}

__device__ __forceinline__ void ins3(float (&tv)[3], int (&ti)[3], float v, int ci)
{
    if (v > tv[0] || (v == tv[0] && ci < ti[0])) {
        tv[2] = tv[1]; ti[2] = ti[1];
        tv[1] = tv[0]; ti[1] = ti[0];
        tv[0] = v;     ti[0] = ci;
    } else if (v > tv[1] || (v == tv[1] && ci < ti[1])) {
        tv[2] = tv[1]; ti[2] = ti[1];
        tv[1] = v;     ti[1] = ci;
    } else if (v > tv[2] || (v == tv[2] && ci < ti[2])) {
        tv[2] = v;     ti[2] = ci;
    }
}

// -------- Kernel 1 (fallback only): maxpool fp32 ----------------------------
__global__ __launch_bounds__(256) void k_pool(const float* __restrict__ x,
                                              float* __restrict__ dsxT)
{
    int gid = blockIdx.x * 256 + threadIdx.x;
    int c = gid >> 12;
    int n = gid & 4095;
    int b = n >> 10, i = (n >> 5) & 31, j = n & 31;
    const float* p = x + (((size_t)(b * 96 + c)) << 16) + i * 2048 + j * 8;
    float4 m0 = *(const float4*)p;
    float4 m1 = *(const float4*)(p + 4);
    #pragma unroll
    for (int r = 1; r < 8; ++r) {
        float4 a0 = *(const float4*)(p + r * 256);
        float4 a1 = *(const float4*)(p + r * 256 + 4);
        m0.x = fmaxf(m0.x, a0.x); m0.y = fmaxf(m0.y, a0.y);
        m0.z = fmaxf(m0.z, a0.z); m0.w = fmaxf(m0.w, a0.w);
        m1.x = fmaxf(m1.x, a1.x); m1.y = fmaxf(m1.y, a1.y);
        m1.z = fmaxf(m1.z, a1.z); m1.w = fmaxf(m1.w, a1.w);
    }
    float m = fmaxf(fmaxf(fmaxf(m0.x, m0.y), fmaxf(m0.z, m0.w)),
                    fmaxf(fmaxf(m1.x, m1.y), fmaxf(m1.z, m1.w)));
    dsxT[c * 4096 + n] = m;
}

// -------- Kernel 0b: x -> xwg bf16 [4096][64][96] + fused maxpool -----------
__global__ __launch_bounds__(768) void k_cast(const float* __restrict__ x,
                                              unsigned short* __restrict__ xwg,
                                              float* __restrict__ dsxT)
{
    int n = blockIdx.x;
    int t = threadIdx.x;
    int cg = t >> 6, p = t & 63;                 // wave == one cg (8 channels)
    int b = n >> 10, i = (n >> 5) & 31, j = n & 31;
    int h = i * 8 + (p >> 3), w = j * 8 + (p & 7);
    size_t base = (((size_t)(b * 96 + 8 * cg)) << 16) + (size_t)(h * 256 + w);
    float v[8];
    #pragma unroll
    for (int jj = 0; jj < 8; ++jj) v[jj] = x[base + (((size_t)jj) << 16)];
    uint4v pk;
    #pragma unroll
    for (int jj = 0; jj < 4; ++jj) pk[jj] = pk_bf16(v[2 * jj], v[2 * jj + 1]);
    *(uint4v*)&xwg[(size_t)n * 6144 + p * 96 + 8 * cg] = pk;
    // window max per channel via full-wave shuffle reduce
    #pragma unroll
    for (int jj = 0; jj < 8; ++jj) {
        float m = v[jj];
        #pragma unroll
        for (int d = 1; d < 64; d <<= 1) m = fmaxf(m, __shfl_xor(m, d, 64));
        if (p == 0) dsxT[(8 * cg + jj) * 4096 + n] = m;
    }
}

// -------- Kernel 2: similarity + partial top3 (fp32, 128x128 tiles) ---------
// grid 512 = 32 q-tiles(128) x 16 cand-chunks(256); block 256 (16x16).
__global__ __launch_bounds__(256) void k_sim(const float* __restrict__ dsxT,
                                             float* __restrict__ pv,
                                             int* __restrict__ pi)
{
    __shared__ __align__(16) float qt[32 * 128];   // 16384 B
    __shared__ __align__(16) float ct[32 * 144];   // 18432 B (pad 4 per 32)
    int t = threadIdx.x;
    int qti = blockIdx.x >> 4;
    int ch  = blockIdx.x & 15;
    int ty = t >> 4, tx = t & 15;
    int qb = qti * 128;

    float tv[8][3]; int ti[8][3];
    #pragma unroll
    for (int a = 0; a < 8; ++a)
        #pragma unroll
        for (int k = 0; k < 3; ++k) { tv[a][k] = NEG_INF; ti[a][k] = 0x7fffffff; }

    #pragma unroll
    for (int pass = 0; pass < 2; ++pass) {
        int cb = ch * 256 + pass * 128;
        float acc[8][8];
        #pragma unroll
        for (int a = 0; a < 8; ++a)
            #pragma unroll
            for (int e = 0; e < 8; ++e) acc[a][e] = 0.f;

        for (int kc = 0; kc < 3; ++kc) {
            __syncthreads();
            #pragma unroll
            for (int f4 = 0; f4 < 4; ++f4) {
                int f = t + f4 * 256;             // 0..1023
                int kk = f >> 5, cq = f & 31;
                *(float4*)&qt[kk * 128 + 4 * cq] =
                    *(const float4*)&dsxT[(kc * 32 + kk) * 4096 + qb + 4 * cq];
                *(float4*)&ct[kk * 144 + 4 * cq + 4 * (cq >> 3)] =
                    *(const float4*)&dsxT[(kc * 32 + kk) * 4096 + cb + 4 * cq];
            }
            __syncthreads();
            #pragma unroll 2
            for (int kk = 0; kk < 32; ++kk) {
                float4 q0 = *(float4*)&qt[kk * 128 + 8 * ty];
                float4 q1 = *(float4*)&qt[kk * 128 + 8 * ty + 4];
                int e0 = 8 * tx, e1 = 8 * tx + 4;
                float4 c0 = *(float4*)&ct[kk * 144 + e0 + 4 * (e0 >> 5)];
                float4 c1 = *(float4*)&ct[kk * 144 + e1 + 4 * (e1 >> 5)];
                float qv[8] = {q0.x, q0.y, q0.z, q0.w, q1.x, q1.y, q1.z, q1.w};
                float cv[8] = {c0.x, c0.y, c0.z, c0.w, c1.x, c1.y, c1.z, c1.w};
                #pragma unroll
                for (int a = 0; a < 8; ++a)
                    #pragma unroll
                    for (int e = 0; e < 8; ++e)
                        acc[a][e] = fmaf(qv[a], cv[e], acc[a][e]);
            }
        }
        #pragma unroll
        for (int e = 0; e < 8; ++e) {
            int ci = cb + 8 * tx + e;
            #pragma unroll
            for (int a = 0; a < 8; ++a) ins3(tv[a], ti[a], acc[a][e], ci);
        }
    }

    // merge top3 across the 16 tx-lanes (same 8 q-rows) via butterfly shuffle
    #pragma unroll
    for (int d = 1; d < 16; d <<= 1) {
        #pragma unroll
        for (int a = 0; a < 8; ++a) {
            float ov[3]; int oi[3];
            #pragma unroll
            for (int k = 0; k < 3; ++k) {
                ov[k] = __shfl_xor(tv[a][k], d, 16);
                oi[k] = __shfl_xor(ti[a][k], d, 16);
            }
            #pragma unroll
            for (int k = 0; k < 3; ++k) ins3(tv[a], ti[a], ov[k], oi[k]);
        }
    }
    if (tx == 0) {
        #pragma unroll
        for (int a = 0; a < 8; ++a) {
            int nq = qti * 128 + 8 * ty + a;
            #pragma unroll
            for (int k = 0; k < 3; ++k) {
                pv[nq * 48 + ch * 3 + k] = tv[a][k];
                pi[nq * 48 + ch * 3 + k] = ti[a][k];
            }
        }
    }
}

// ---------------- Kernel 2b: final top3 merge + softmax weights -------------
__global__ __launch_bounds__(256) void k_topk(const float* __restrict__ pv,
                                              const int* __restrict__ pi,
                                              float* __restrict__ w3,
                                              int* __restrict__ i3)
{
    int n = blockIdx.x * 256 + threadIdx.x;
    float bv[3] = {NEG_INF, NEG_INF, NEG_INF};
    int   bi[3] = {0x7fffffff, 0x7fffffff, 0x7fffffff};
    for (int e = 0; e < 48; ++e)
        ins3(bv, bi, pv[n * 48 + e], pi[n * 48 + e]);
    float e1 = expf(bv[1] - bv[0]);
    float e2 = expf(bv[2] - bv[0]);
    float inv = 1.f / (1.f + e1 + e2);
    w3[n * 3 + 0] = inv;
    w3[n * 3 + 1] = e1 * inv;
    w3[n * 3 + 2] = e2 * inv;
    i3[n * 3 + 0] = bi[0];
    i3[n * 3 + 1] = bi[1];
    i3[n * 3 + 2] = bi[2];
}

// -------- Kernel 0a: weights -> WtT[4][96co][96ci] bf16 ; lwT[9][96] fp32 ---
__global__ __launch_bounds__(256) void k_prep(const float* __restrict__ Wq,
                                              const float* __restrict__ Wk,
                                              const float* __restrict__ Wv,
                                              const float* __restrict__ Wp,
                                              const float* __restrict__ lw,
                                              unsigned short* __restrict__ WtT,
                                              float* __restrict__ lwT)
{
    int g = blockIdx.x * 256 + threadIdx.x;
    if (g < 4608) {
        int w  = g / 1152;
        int co = (g % 1152) / 12;
        int cg = g % 12;
        const float* src = (w == 0) ? Wq : (w == 1) ? Wk : (w == 2) ? Wv : Wp;
        unsigned short* dst = WtT + w * 9216 + co * 96 + 8 * cg;
        #pragma unroll
        for (int j = 0; j < 8; ++j) dst[j] = bfbits(src[(8 * cg + j) * 96 + co]);
    } else if (g < 5472) {
        int i2 = g - 4608;
        int tap = i2 / 96, c = i2 % 96;
        lwT[tap * 96 + c] = lw[c * 9 + tap];
    }
}

// ----------------------- Kernel 3: fused MFMA window attention --------------
__device__ __forceinline__ size_t win_off(int m)
{
    return (((size_t)(m >> 10) * 96) << 16) +
           (size_t)(((m >> 5) & 31) * 2048 + (m & 31) * 8);
}

// 6 16x16 col-tiles, K=96, B-operand burst-loaded from global WtT block.
// Burst: issue all 18 16-B loads first (compiler keeps them in flight under
// the 128-VGPR cap), then run the pure-MFMA cluster under setprio(1).
__device__ __forceinline__ void gemm_g(const short8* af,
                                       const unsigned short* __restrict__ Wt,
                                       int l15, int quad, f32x4* acc)
{
    short8 bfr[18];
    #pragma unroll
    for (int nt = 0; nt < 6; ++nt)
        #pragma unroll
        for (int ks = 0; ks < 3; ++ks)
            bfr[nt * 3 + ks] =
                *(const short8*)&Wt[(nt * 16 + l15) * 96 + ks * 32 + quad * 8];
    __builtin_amdgcn_s_setprio(1);
    #pragma unroll
    for (int nt = 0; nt < 6; ++nt) {
        f32x4 c = {0.f, 0.f, 0.f, 0.f};
        #pragma unroll
        for (int ks = 0; ks < 3; ++ks)
            c = __builtin_amdgcn_mfma_f32_16x16x32_bf16(af[ks], bfr[nt * 3 + ks],
                                                        c, 0, 0, 0);
        acc[nt] = c;
    }
    __builtin_amdgcn_s_setprio(0);
}

template<bool XWG>
__global__ __launch_bounds__(256, 4) void k_attn(
    const float* __restrict__ x,
    const unsigned short* __restrict__ xwg,
    const unsigned short* __restrict__ WtT,
    const float* __restrict__ lwT,
    const float* __restrict__ bq, const float* __restrict__ bk,
    const float* __restrict__ bv, const float* __restrict__ bp,
    const float* __restrict__ lb,
    const float* __restrict__ w3, const int* __restrict__ i3,
    float* __restrict__ out)
{
    // LDS: buf1[64][104] (As->Qs->Ss->Os), buf2[64][104] (Bc->Ks->Ls),
    //      Vt[96][72].  Total 40448 B -> 4 blocks/CU.
    extern __shared__ __align__(16) unsigned short sm[];
    unsigned short* buf1 = sm;            // 6656 shorts
    unsigned short* buf2 = sm + 6656;     // 6656 shorts
    unsigned short* Vt   = sm + 13312;    // 6912 shorts

    int t = threadIdx.x;
    int n = blockIdx.x;
    int lane = t & 63, mt = t >> 6;
    int l15 = lane & 15, quad = lane >> 4;

    float wk0 = w3[n * 3 + 0], wk1 = w3[n * 3 + 1], wk2 = w3[n * 3 + 2];
    int   m0  = i3[n * 3 + 0], m1 = i3[n * 3 + 1], m2 = i3[n * 3 + 2];

    // ---- P0: gather self (buf1=As) + weighted context (buf2=Bc) ----
    if (XWG) {
        #pragma unroll
        for (int it = 0; it < 3; ++it) {
            int g = it * 256 + t;
            int p = g / 12, cg = g % 12;
            int o = p * 96 + 8 * cg;
            uint4v sv = *(const uint4v*)&xwg[(size_t)n * 6144 + o];
            *(uint4v*)&buf1[p * 104 + 8 * cg] = sv;
            uint4v a0 = *(const uint4v*)&xwg[(size_t)m0 * 6144 + o];
            uint4v a1 = *(const uint4v*)&xwg[(size_t)m1 * 6144 + o];
            uint4v a2 = *(const uint4v*)&xwg[(size_t)m2 * 6144 + o];
            uint4v rs;
            #pragma unroll
            for (int e = 0; e < 4; ++e) {
                float lo = wk0 * lofp(a0[e]) + wk1 * lofp(a1[e]) + wk2 * lofp(a2[e]);
                float hi = wk0 * hifp(a0[e]) + wk1 * hifp(a1[e]) + wk2 * hifp(a2[e]);
                rs[e] = pk_bf16(lo, hi);
            }
            *(uint4v*)&buf2[p * 104 + 8 * cg] = rs;
        }
    } else {
        size_t so = win_off(n), o0 = win_off(m0), o1 = win_off(m1), o2 = win_off(m2);
        #pragma unroll
        for (int it = 0; it < 3; ++it) {
            int g = it * 256 + t;
            int p = g / 12, cg = g % 12;
            size_t po = (size_t)((p >> 3) * 256 + (p & 7));
            uint4v ra, rb;
            #pragma unroll
            for (int jj = 0; jj < 4; ++jj) {
                size_t clo = (((size_t)(8 * cg + 2 * jj)) << 16) + po;
                size_t chi = clo + ((size_t)1 << 16);
                ra[jj] = pk_bf16(x[so + clo], x[so + chi]);
                float blo = wk0 * x[o0 + clo] + wk1 * x[o1 + clo] + wk2 * x[o2 + clo];
                float bhi = wk0 * x[o0 + chi] + wk1 * x[o1 + chi] + wk2 * x[o2 + chi];
                rb[jj] = pk_bf16(blo, bhi);
            }
            *(uint4v*)&buf1[p * 104 + 8 * cg] = ra;
            *(uint4v*)&buf2[p * 104 + 8 * cg] = rb;
        }
    }
    __syncthreads();

    // ---- P1a: cache A-fragments in regs + lepe into registers ----
    short8 af_a[3], af_b[3];
    int arow = (mt * 16 + l15) * 104;
    #pragma unroll
    for (int ks = 0; ks < 3; ++ks) {
        af_a[ks] = *(const short8*)&buf1[arow + ks * 32 + quad * 8];
        af_b[ks] = *(const short8*)&buf2[arow + ks * 32 + quad * 8];
    }
    unsigned Lp[12];
    {
        int rowp = mt * 16 + l15;          // own row
        int c0 = 24 * quad;                // own 24-channel slice
        int rr0 = rowp >> 3, ss0 = rowp & 7;
        float lac[24];
        #pragma unroll
        for (int q4 = 0; q4 < 6; ++q4) {
            float4 bb = *(const float4*)&lb[c0 + 4 * q4];
            lac[4 * q4] = bb.x; lac[4 * q4 + 1] = bb.y;
            lac[4 * q4 + 2] = bb.z; lac[4 * q4 + 3] = bb.w;
        }
        #pragma unroll
        for (int dr = -1; dr <= 1; ++dr) {
            int rr = rr0 + dr;
            if ((unsigned)rr >= 8u) continue;
            #pragma unroll
            for (int dss = -1; dss <= 1; ++dss) {
                int ss = ss0 + dss;
                if ((unsigned)ss >= 8u) continue;
                int pp = rr * 8 + ss;
                int tap = (dr + 1) * 3 + (dss + 1);
                const uint4v* ap = (const uint4v*)&buf1[pp * 104 + c0];
                uint4v av0 = ap[0], av1 = ap[1], av2 = ap[2];
                float wf[24];
                #pragma unroll
                for (int q4 = 0; q4 < 6; ++q4) {
                    float4 ww = *(const float4*)&lwT[tap * 96 + c0 + 4 * q4];
                    wf[4 * q4] = ww.x; wf[4 * q4 + 1] = ww.y;
                    wf[4 * q4 + 2] = ww.z; wf[4 * q4 + 3] = ww.w;
                }
                #pragma unroll
                for (int u = 0; u < 12; ++u) {
                    unsigned uu = (u < 4) ? av0[u] : (u < 8) ? av1[u - 4] : av2[u - 8];
                    lac[2 * u]     = fmaf(wf[2 * u],     lofp(uu), lac[2 * u]);
                    lac[2 * u + 1] = fmaf(wf[2 * u + 1], hifp(uu), lac[2 * u + 1]);
                }
            }
        }
        #pragma unroll
        for (int u = 0; u < 12; ++u) Lp[u] = pk_bf16(lac[2 * u], lac[2 * u + 1]);
    }
    __syncthreads();

    // ---- P1b: Q -> buf1 (in place), K -> buf2 (in place), V -> Vt ----
    {
        f32x4 qa[6];
        gemm_g(af_a, WtT, l15, quad, qa);
        #pragma unroll
        for (int nt = 0; nt < 6; ++nt) {
            int col = nt * 16 + l15;
            float bb = bq[col];
            #pragma unroll
            for (int r = 0; r < 4; ++r)
                buf1[(mt * 16 + quad * 4 + r) * 104 + col] = bfbits(qa[nt][r] + bb);
        }
    }
    {
        f32x4 ka[6];
        gemm_g(af_b, WtT + 9216, l15, quad, ka);
        #pragma unroll
        for (int nt = 0; nt < 6; ++nt) {
            int col = nt * 16 + l15;
            float bb = bk[col];
            #pragma unroll
            for (int r = 0; r < 4; ++r)
                buf2[(mt * 16 + quad * 4 + r) * 104 + col] = bfbits(ka[nt][r] + bb);
        }
    }
    {
        f32x4 va[6];
        gemm_g(af_b, WtT + 18432, l15, quad, va);
        #pragma unroll
        for (int nt = 0; nt < 6; ++nt) {
            float bb = bv[nt * 16 + l15];
            uint2v pk;
            pk[0] = pk_bf16(va[nt][0] + bb, va[nt][1] + bb);
            pk[1] = pk_bf16(va[nt][2] + bb, va[nt][3] + bb);
            *(uint2v*)&Vt[(nt * 16 + l15) * 72 + mt * 16 + quad * 4] = pk;
        }
    }
    __syncthreads();

    // ---- P2: S = QK^T, softmax in registers ----
    float pr[4][4], inv4[4];
    {
        short8 qf[3];
        #pragma unroll
        for (int ks = 0; ks < 3; ++ks)
            qf[ks] = *(const short8*)&buf1[arow + ks * 32 + quad * 8];
        short8 kfr[12];
        #pragma unroll
        for (int nt = 0; nt < 4; ++nt)
            #pragma unroll
            for (int ks = 0; ks < 3; ++ks)
                kfr[nt * 3 + ks] =
                    *(const short8*)&buf2[(nt * 16 + l15) * 104 + ks * 32 + quad * 8];
        f32x4 sa[4];
        __builtin_amdgcn_s_setprio(1);
        #pragma unroll
        for (int nt = 0; nt < 4; ++nt) {
            f32x4 c = {0.f, 0.f, 0.f, 0.f};
            #pragma unroll
            for (int ks = 0; ks < 3; ++ks)
                c = __builtin_amdgcn_mfma_f32_16x16x32_bf16(qf[ks], kfr[nt * 3 + ks],
                                                            c, 0, 0, 0);
            sa[nt] = c;
        }
        __builtin_amdgcn_s_setprio(0);
        const float scale = 0.10206207261596575f;
        #pragma unroll
        for (int r = 0; r < 4; ++r) {
            float mx = fmaxf(fmaxf(sa[0][r], sa[1][r]), fmaxf(sa[2][r], sa[3][r]));
            #pragma unroll
            for (int d = 1; d < 16; d <<= 1) mx = fmaxf(mx, __shfl_xor(mx, d, 16));
            float sum = 0.f;
            #pragma unroll
            for (int nt = 0; nt < 4; ++nt) {
                float e = __expf((sa[nt][r] - mx) * scale);
                pr[r][nt] = e; sum += e;
            }
            #pragma unroll
            for (int d = 1; d < 16; d <<= 1) sum += __shfl_xor(sum, d, 16);
            inv4[r] = 1.f / sum;
        }
    }
    __syncthreads();   // last barrier: protects Ss/Ls overwrite of Qs/Ks

    // ---- P3: probs -> buf1 (over Qs), lepe -> buf2 (over Ks); own rows only
    #pragma unroll
    for (int r = 0; r < 4; ++r) {
        #pragma unroll
        for (int nt = 0; nt < 4; ++nt)
            buf1[(mt * 16 + quad * 4 + r) * 104 + nt * 16 + l15] =
                bfbits(pr[r][nt] * inv4[r]);
    }
    {
        uint4v* lp = (uint4v*)&buf2[arow + 24 * quad];
        uint4v l0 = {Lp[0], Lp[1], Lp[2], Lp[3]};
        uint4v l1 = {Lp[4], Lp[5], Lp[6], Lp[7]};
        uint4v l2 = {Lp[8], Lp[9], Lp[10], Lp[11]};
        lp[0] = l0; lp[1] = l1; lp[2] = l2;
    }

    // ---- P4: O = S @ V -> buf1 (over Ss); wave-local, no barrier ----
    {
        short8 sf[2];
        sf[0] = *(const short8*)&buf1[arow + quad * 8];
        sf[1] = *(const short8*)&buf1[arow + 32 + quad * 8];
        short8 vfr[12];
        #pragma unroll
        for (int nt = 0; nt < 6; ++nt)
            #pragma unroll
            for (int ks = 0; ks < 2; ++ks)
                vfr[nt * 2 + ks] =
                    *(const short8*)&Vt[(nt * 16 + l15) * 72 + ks * 32 + quad * 8];
        f32x4 oa[6];
        __builtin_amdgcn_s_setprio(1);
        #pragma unroll
        for (int nt = 0; nt < 6; ++nt) {
            f32x4 c = {0.f, 0.f, 0.f, 0.f};
            #pragma unroll
            for (int ks = 0; ks < 2; ++ks)
                c = __builtin_amdgcn_mfma_f32_16x16x32_bf16(sf[ks], vfr[nt * 2 + ks],
                                                            c, 0, 0, 0);
            oa[nt] = c;
        }
        __builtin_amdgcn_s_setprio(0);
        #pragma unroll
        for (int nt = 0; nt < 6; ++nt)
            #pragma unroll
            for (int r = 0; r < 4; ++r)
                buf1[(mt * 16 + quad * 4 + r) * 104 + nt * 16 + l15] = bfbits(oa[nt][r]);
    }

    // ---- P6: out = (O + L) @ Wp + bp; wave-local, no barrier ----
    {
        short8 of[3], lf[3];
        #pragma unroll
        for (int ks = 0; ks < 3; ++ks) {
            of[ks] = *(const short8*)&buf1[arow + ks * 32 + quad * 8];
            lf[ks] = *(const short8*)&buf2[arow + ks * 32 + quad * 8];
        }
        const unsigned short* Wp_ = WtT + 27648;
        short8 bfr[18];
        #pragma unroll
        for (int nt = 0; nt < 6; ++nt)
            #pragma unroll
            for (int ks = 0; ks < 3; ++ks)
                bfr[nt * 3 + ks] =
                    *(const short8*)&Wp_[(nt * 16 + l15) * 96 + ks * 32 + quad * 8];
        int b = n >> 10, ii = (n >> 5) & 31, jj = n & 31;
        // token index p2 = mt*16 + quad*4 + r; for fixed (mt,quad) the 4 r's
        // are consecutive floats: mt*512 + (quad>>1)*256 + (quad&1)*4 + r.
        size_t pbase = (size_t)(ii * 2048 + jj * 8 + mt * 512 +
                                (quad >> 1) * 256 + (quad & 1) * 4);
        __builtin_amdgcn_s_setprio(1);
        #pragma unroll
        for (int nt = 0; nt < 6; ++nt) {
            f32x4 c = {0.f, 0.f, 0.f, 0.f};
            #pragma unroll
            for (int ks = 0; ks < 3; ++ks) {
                c = __builtin_amdgcn_mfma_f32_16x16x32_bf16(of[ks], bfr[nt * 3 + ks],
                                                            c, 0, 0, 0);
                c = __builtin_amdgcn_mfma_f32_16x16x32_bf16(lf[ks], bfr[nt * 3 + ks],
                                                            c, 0, 0, 0);
            }
            int co = nt * 16 + l15;
            float bb = bp[co];
            float4 st;
            st.x = c[0] + bb; st.y = c[1] + bb; st.z = c[2] + bb; st.w = c[3] + bb;
            *(float4*)&out[(((size_t)(b * 96 + co)) << 16) + pbase] = st;
        }
        __builtin_amdgcn_s_setprio(0);
    }
}

// ---------------------------------------------------------------------------
extern "C" void kernel_launch(void* const* d_in, const int* in_sizes, int n_in,
                              void* d_out, int out_size, void* d_ws, size_t ws_size,
                              hipStream_t stream)
{
    (void)in_sizes; (void)n_in; (void)out_size;
    const float* x  = (const float*)d_in[0];
    const float* Wq = (const float*)d_in[1];
    const float* bq = (const float*)d_in[2];
    const float* Wk = (const float*)d_in[3];
    const float* bk = (const float*)d_in[4];
    const float* Wv = (const float*)d_in[5];
    const float* bv = (const float*)d_in[6];
    const float* Wp = (const float*)d_in[7];
    const float* bp = (const float*)d_in[8];
    const float* lw = (const float*)d_in[9];
    const float* lb = (const float*)d_in[10];
    float* out = (float*)d_out;

    char* ws = (char*)d_ws;
    float* dsxT = (float*)ws;                               // 1,572,864 B
    float* pv   = (float*)(ws + 1572864);                   //   786,432 B
    int*   pi   = (int*)  (ws + 2359296);                   //   786,432 B
    float* w3   = (float*)(ws + 3145728);                   //    49,152 B
    int*   i3   = (int*)  (ws + 3194880);                   //    49,152 B
    unsigned short* WtT = (unsigned short*)(ws + 3244032);  //    73,728 B
    float* lwT  = (float*)(ws + 3317760);                   //     3,456 B
    unsigned short* xwg = (unsigned short*)(ws + 3321344);  // 50,331,648 B
    bool use_xwg = (ws_size >= 53652992ull);

    (void)hipFuncSetAttribute(reinterpret_cast<const void*>(&k_attn<true>),
                        hipFuncAttributeMaxDynamicSharedMemorySize, 40448);
    (void)hipFuncSetAttribute(reinterpret_cast<const void*>(&k_attn<false>),
                        hipFuncAttributeMaxDynamicSharedMemorySize, 40448);

    k_prep<<<22, 256, 0, stream>>>(Wq, Wk, Wv, Wp, lw, WtT, lwT);
    if (use_xwg) {
        k_cast<<<4096, 768, 0, stream>>>(x, xwg, dsxT);
    } else {
        k_pool<<<1536, 256, 0, stream>>>(x, dsxT);
    }
    k_sim<<<512, 256, 0, stream>>>(dsxT, pv, pi);
    k_topk<<<16, 256, 0, stream>>>(pv, pi, w3, i3);
    if (use_xwg) {
        k_attn<true><<<4096, 256, 40448, stream>>>(x, xwg, WtT, lwT, bq, bk, bv, bp,
                                                   lb, w3, i3, out);
    } else {
        k_attn<false><<<4096, 256, 40448, stream>>>(x, nullptr, WtT, lwT, bq, bk, bv, bp,
                                                    lb, w3, i3, out);
    }
}

// Round 2
// 449.075 us; speedup vs baseline: 1.0322x; 1.0322x over previous
//
#include <hip/hip_runtime.h>

typedef __attribute__((ext_vector_type(8))) short  short8;
typedef __attribute__((ext_vector_type(4))) float  f32x4;
typedef __attribute__((ext_vector_type(4))) unsigned int uint4v;
typedef __attribute__((ext_vector_type(2))) unsigned int uint2v;

#define NEG_INF (-3.402823466e38f)

__device__ __forceinline__ unsigned short bfbits(float f) {
    unsigned u = __builtin_bit_cast(unsigned, f);
    u += 0x7fffu + ((u >> 16) & 1u);
    return (unsigned short)(u >> 16);
}
__device__ __forceinline__ unsigned pk_bf16(float lo, float hi) {
    return (unsigned)bfbits(lo) | ((unsigned)bfbits(hi) << 16);
}
__device__ __forceinline__ float lofp(unsigned u) {
    return __builtin_bit_cast(float, u << 16);
}
__device__ __forceinline__ float hifp(unsigned u) {
    return __builtin_bit_cast(float, u & 0xffff0000u);
}

__device__ __forceinline__ void ins3(float (&tv)[3], int (&ti)[3], float v, int ci)
{
    if (v > tv[0] || (v == tv[0] && ci < ti[0])) {
        tv[2] = tv[1]; ti[2] = ti[1];
        tv[1] = tv[0]; ti[1] = ti[0];
        tv[0] = v;     ti[0] = ci;
    } else if (v > tv[1] || (v == tv[1] && ci < ti[1])) {
        tv[2] = tv[1]; ti[2] = ti[1];
        tv[1] = v;     ti[1] = ci;
    } else if (v > tv[2] || (v == tv[2] && ci < ti[2])) {
        tv[2] = v;     ti[2] = ci;
    }
}

// -------- Kernel 1 (fallback only): maxpool fp32 ----------------------------
__global__ __launch_bounds__(256) void k_pool(const float* __restrict__ x,
                                              float* __restrict__ dsxT)
{
    int gid = blockIdx.x * 256 + threadIdx.x;
    int c = gid >> 12;
    int n = gid & 4095;
    int b = n >> 10, i = (n >> 5) & 31, j = n & 31;
    const float* p = x + (((size_t)(b * 96 + c)) << 16) + i * 2048 + j * 8;
    float4 m0 = *(const float4*)p;
    float4 m1 = *(const float4*)(p + 4);
    #pragma unroll
    for (int r = 1; r < 8; ++r) {
        float4 a0 = *(const float4*)(p + r * 256);
        float4 a1 = *(const float4*)(p + r * 256 + 4);
        m0.x = fmaxf(m0.x, a0.x); m0.y = fmaxf(m0.y, a0.y);
        m0.z = fmaxf(m0.z, a0.z); m0.w = fmaxf(m0.w, a0.w);
        m1.x = fmaxf(m1.x, a1.x); m1.y = fmaxf(m1.y, a1.y);
        m1.z = fmaxf(m1.z, a1.z); m1.w = fmaxf(m1.w, a1.w);
    }
    float m = fmaxf(fmaxf(fmaxf(m0.x, m0.y), fmaxf(m0.z, m0.w)),
                    fmaxf(fmaxf(m1.x, m1.y), fmaxf(m1.z, m1.w)));
    dsxT[c * 4096 + n] = m;
}

// -------- Kernel 0b: x -> xwg bf16 [4096][64][96] + fused maxpool -----------
__global__ __launch_bounds__(768) void k_cast(const float* __restrict__ x,
                                              unsigned short* __restrict__ xwg,
                                              float* __restrict__ dsxT)
{
    int n = blockIdx.x;
    int t = threadIdx.x;
    int cg = t >> 6, p = t & 63;                 // wave == one cg (8 channels)
    int b = n >> 10, i = (n >> 5) & 31, j = n & 31;
    int h = i * 8 + (p >> 3), w = j * 8 + (p & 7);
    size_t base = (((size_t)(b * 96 + 8 * cg)) << 16) + (size_t)(h * 256 + w);
    float v[8];
    #pragma unroll
    for (int jj = 0; jj < 8; ++jj) v[jj] = x[base + (((size_t)jj) << 16)];
    uint4v pk;
    #pragma unroll
    for (int jj = 0; jj < 4; ++jj) pk[jj] = pk_bf16(v[2 * jj], v[2 * jj + 1]);
    *(uint4v*)&xwg[(size_t)n * 6144 + p * 96 + 8 * cg] = pk;
    // window max per channel via full-wave shuffle reduce
    #pragma unroll
    for (int jj = 0; jj < 8; ++jj) {
        float m = v[jj];
        #pragma unroll
        for (int d = 1; d < 64; d <<= 1) m = fmaxf(m, __shfl_xor(m, d, 64));
        if (p == 0) dsxT[(8 * cg + jj) * 4096 + n] = m;
    }
}

// -------- Kernel 2: similarity + partial top3 (fp32, 128x128 tiles) ---------
// grid 512 = 32 q-tiles(128) x 16 cand-chunks(256); block 256 (16x16).
__global__ __launch_bounds__(256) void k_sim(const float* __restrict__ dsxT,
                                             float* __restrict__ pv,
                                             int* __restrict__ pi)
{
    __shared__ __align__(16) float qt[32 * 128];   // 16384 B
    __shared__ __align__(16) float ct[32 * 144];   // 18432 B (pad 4 per 32)
    int t = threadIdx.x;
    int qti = blockIdx.x >> 4;
    int ch  = blockIdx.x & 15;
    int ty = t >> 4, tx = t & 15;
    int qb = qti * 128;

    float tv[8][3]; int ti[8][3];
    #pragma unroll
    for (int a = 0; a < 8; ++a)
        #pragma unroll
        for (int k = 0; k < 3; ++k) { tv[a][k] = NEG_INF; ti[a][k] = 0x7fffffff; }

    #pragma unroll
    for (int pass = 0; pass < 2; ++pass) {
        int cb = ch * 256 + pass * 128;
        float acc[8][8];
        #pragma unroll
        for (int a = 0; a < 8; ++a)
            #pragma unroll
            for (int e = 0; e < 8; ++e) acc[a][e] = 0.f;

        for (int kc = 0; kc < 3; ++kc) {
            __syncthreads();
            #pragma unroll
            for (int f4 = 0; f4 < 4; ++f4) {
                int f = t + f4 * 256;             // 0..1023
                int kk = f >> 5, cq = f & 31;
                *(float4*)&qt[kk * 128 + 4 * cq] =
                    *(const float4*)&dsxT[(kc * 32 + kk) * 4096 + qb + 4 * cq];
                *(float4*)&ct[kk * 144 + 4 * cq + 4 * (cq >> 3)] =
                    *(const float4*)&dsxT[(kc * 32 + kk) * 4096 + cb + 4 * cq];
            }
            __syncthreads();
            #pragma unroll 2
            for (int kk = 0; kk < 32; ++kk) {
                float4 q0 = *(float4*)&qt[kk * 128 + 8 * ty];
                float4 q1 = *(float4*)&qt[kk * 128 + 8 * ty + 4];
                int e0 = 8 * tx, e1 = 8 * tx + 4;
                float4 c0 = *(float4*)&ct[kk * 144 + e0 + 4 * (e0 >> 5)];
                float4 c1 = *(float4*)&ct[kk * 144 + e1 + 4 * (e1 >> 5)];
                float qv[8] = {q0.x, q0.y, q0.z, q0.w, q1.x, q1.y, q1.z, q1.w};
                float cv[8] = {c0.x, c0.y, c0.z, c0.w, c1.x, c1.y, c1.z, c1.w};
                #pragma unroll
                for (int a = 0; a < 8; ++a)
                    #pragma unroll
                    for (int e = 0; e < 8; ++e)
                        acc[a][e] = fmaf(qv[a], cv[e], acc[a][e]);
            }
        }
        #pragma unroll
        for (int e = 0; e < 8; ++e) {
            int ci = cb + 8 * tx + e;
            #pragma unroll
            for (int a = 0; a < 8; ++a) ins3(tv[a], ti[a], acc[a][e], ci);
        }
    }

    // merge top3 across the 16 tx-lanes (same 8 q-rows) via butterfly shuffle
    #pragma unroll
    for (int d = 1; d < 16; d <<= 1) {
        #pragma unroll
        for (int a = 0; a < 8; ++a) {
            float ov[3]; int oi[3];
            #pragma unroll
            for (int k = 0; k < 3; ++k) {
                ov[k] = __shfl_xor(tv[a][k], d, 16);
                oi[k] = __shfl_xor(ti[a][k], d, 16);
            }
            #pragma unroll
            for (int k = 0; k < 3; ++k) ins3(tv[a], ti[a], ov[k], oi[k]);
        }
    }
    if (tx == 0) {
        #pragma unroll
        for (int a = 0; a < 8; ++a) {
            int nq = qti * 128 + 8 * ty + a;
            #pragma unroll
            for (int k = 0; k < 3; ++k) {
                pv[nq * 48 + ch * 3 + k] = tv[a][k];
                pi[nq * 48 + ch * 3 + k] = ti[a][k];
            }
        }
    }
}

// ---------------- Kernel 2b: final top3 merge + softmax weights -------------
__global__ __launch_bounds__(256) void k_topk(const float* __restrict__ pv,
                                              const int* __restrict__ pi,
                                              float* __restrict__ w3,
                                              int* __restrict__ i3)
{
    int n = blockIdx.x * 256 + threadIdx.x;
    float bv[3] = {NEG_INF, NEG_INF, NEG_INF};
    int   bi[3] = {0x7fffffff, 0x7fffffff, 0x7fffffff};
    for (int e = 0; e < 48; ++e)
        ins3(bv, bi, pv[n * 48 + e], pi[n * 48 + e]);
    float e1 = expf(bv[1] - bv[0]);
    float e2 = expf(bv[2] - bv[0]);
    float inv = 1.f / (1.f + e1 + e2);
    w3[n * 3 + 0] = inv;
    w3[n * 3 + 1] = e1 * inv;
    w3[n * 3 + 2] = e2 * inv;
    i3[n * 3 + 0] = bi[0];
    i3[n * 3 + 1] = bi[1];
    i3[n * 3 + 2] = bi[2];
}

// -------- Kernel 0a: weights -> WtT[4][96co][96ci] bf16 ; lwT[9][96] fp32 ---
__global__ __launch_bounds__(256) void k_prep(const float* __restrict__ Wq,
                                              const float* __restrict__ Wk,
                                              const float* __restrict__ Wv,
                                              const float* __restrict__ Wp,
                                              const float* __restrict__ lw,
                                              unsigned short* __restrict__ WtT,
                                              float* __restrict__ lwT)
{
    int g = blockIdx.x * 256 + threadIdx.x;
    if (g < 4608) {
        int w  = g / 1152;
        int co = (g % 1152) / 12;
        int cg = g % 12;
        const float* src = (w == 0) ? Wq : (w == 1) ? Wk : (w == 2) ? Wv : Wp;
        unsigned short* dst = WtT + w * 9216 + co * 96 + 8 * cg;
        #pragma unroll
        for (int j = 0; j < 8; ++j) dst[j] = bfbits(src[(8 * cg + j) * 96 + co]);
    } else if (g < 5472) {
        int i2 = g - 4608;
        int tap = i2 / 96, c = i2 % 96;
        lwT[tap * 96 + c] = lw[c * 9 + tap];
    }
}

// ----------------------- Kernel 3: fused MFMA window attention --------------
__device__ __forceinline__ size_t win_off(int m)
{
    return (((size_t)(m >> 10) * 96) << 16) +
           (size_t)(((m >> 5) & 31) * 2048 + (m & 31) * 8);
}

// 6 16x16 col-tiles, K=96, B-operand streamed from global WtT block.
// Interleaved load->MFMA; the scheduler pipelines under the 128-VGPR budget
// granted by amdgpu_waves_per_eu(4,4) (LDS caps occupancy at 4 blocks anyway).
__device__ __forceinline__ void gemm_g(const short8* af,
                                       const unsigned short* __restrict__ Wt,
                                       int l15, int quad, f32x4* acc)
{
    #pragma unroll
    for (int nt = 0; nt < 6; ++nt) {
        f32x4 c = {0.f, 0.f, 0.f, 0.f};
        #pragma unroll
        for (int ks = 0; ks < 3; ++ks) {
            short8 bf = *(const short8*)&Wt[(nt * 16 + l15) * 96 + ks * 32 + quad * 8];
            c = __builtin_amdgcn_mfma_f32_16x16x32_bf16(af[ks], bf, c, 0, 0, 0);
        }
        acc[nt] = c;
    }
}

template<bool XWG>
__global__ __attribute__((amdgpu_waves_per_eu(4, 4)))
__launch_bounds__(256) void k_attn(
    const float* __restrict__ x,
    const unsigned short* __restrict__ xwg,
    const unsigned short* __restrict__ WtT,
    const float* __restrict__ lwT,
    const float* __restrict__ bq, const float* __restrict__ bk,
    const float* __restrict__ bv, const float* __restrict__ bp,
    const float* __restrict__ lb,
    const float* __restrict__ w3, const int* __restrict__ i3,
    float* __restrict__ out)
{
    // LDS: buf1[64][104] (As->Qs->Ss->Os), buf2[64][104] (Bc->Ks->Ls),
    //      Vt[96][72].  Total 40448 B -> 4 blocks/CU.
    extern __shared__ __align__(16) unsigned short sm[];
    unsigned short* buf1 = sm;            // 6656 shorts
    unsigned short* buf2 = sm + 6656;     // 6656 shorts
    unsigned short* Vt   = sm + 13312;    // 6912 shorts

    int t = threadIdx.x;
    int n = blockIdx.x;
    int lane = t & 63, mt = t >> 6;
    int l15 = lane & 15, quad = lane >> 4;

    float wk0 = w3[n * 3 + 0], wk1 = w3[n * 3 + 1], wk2 = w3[n * 3 + 2];
    int   m0  = i3[n * 3 + 0], m1 = i3[n * 3 + 1], m2 = i3[n * 3 + 2];

    // ---- P0: gather self (buf1=As) + weighted context (buf2=Bc) ----
    if (XWG) {
        #pragma unroll
        for (int it = 0; it < 3; ++it) {
            int g = it * 256 + t;
            int p = g / 12, cg = g % 12;
            int o = p * 96 + 8 * cg;
            uint4v sv = *(const uint4v*)&xwg[(size_t)n * 6144 + o];
            *(uint4v*)&buf1[p * 104 + 8 * cg] = sv;
            uint4v a0 = *(const uint4v*)&xwg[(size_t)m0 * 6144 + o];
            uint4v a1 = *(const uint4v*)&xwg[(size_t)m1 * 6144 + o];
            uint4v a2 = *(const uint4v*)&xwg[(size_t)m2 * 6144 + o];
            uint4v rs;
            #pragma unroll
            for (int e = 0; e < 4; ++e) {
                float lo = wk0 * lofp(a0[e]) + wk1 * lofp(a1[e]) + wk2 * lofp(a2[e]);
                float hi = wk0 * hifp(a0[e]) + wk1 * hifp(a1[e]) + wk2 * hifp(a2[e]);
                rs[e] = pk_bf16(lo, hi);
            }
            *(uint4v*)&buf2[p * 104 + 8 * cg] = rs;
        }
    } else {
        size_t so = win_off(n), o0 = win_off(m0), o1 = win_off(m1), o2 = win_off(m2);
        #pragma unroll
        for (int it = 0; it < 3; ++it) {
            int g = it * 256 + t;
            int p = g / 12, cg = g % 12;
            size_t po = (size_t)((p >> 3) * 256 + (p & 7));
            uint4v ra, rb;
            #pragma unroll
            for (int jj = 0; jj < 4; ++jj) {
                size_t clo = (((size_t)(8 * cg + 2 * jj)) << 16) + po;
                size_t chi = clo + ((size_t)1 << 16);
                ra[jj] = pk_bf16(x[so + clo], x[so + chi]);
                float blo = wk0 * x[o0 + clo] + wk1 * x[o1 + clo] + wk2 * x[o2 + clo];
                float bhi = wk0 * x[o0 + chi] + wk1 * x[o1 + chi] + wk2 * x[o2 + chi];
                rb[jj] = pk_bf16(blo, bhi);
            }
            *(uint4v*)&buf1[p * 104 + 8 * cg] = ra;
            *(uint4v*)&buf2[p * 104 + 8 * cg] = rb;
        }
    }
    __syncthreads();

    // ---- P1a: cache A-fragments in regs + lepe into registers ----
    short8 af_a[3], af_b[3];
    int arow = (mt * 16 + l15) * 104;
    #pragma unroll
    for (int ks = 0; ks < 3; ++ks) {
        af_a[ks] = *(const short8*)&buf1[arow + ks * 32 + quad * 8];
        af_b[ks] = *(const short8*)&buf2[arow + ks * 32 + quad * 8];
    }
    unsigned Lp[12];
    {
        int rowp = mt * 16 + l15;          // own row
        int c0 = 24 * quad;                // own 24-channel slice
        int rr0 = rowp >> 3, ss0 = rowp & 7;
        float lac[24];
        #pragma unroll
        for (int q4 = 0; q4 < 6; ++q4) {
            float4 bb = *(const float4*)&lb[c0 + 4 * q4];
            lac[4 * q4] = bb.x; lac[4 * q4 + 1] = bb.y;
            lac[4 * q4 + 2] = bb.z; lac[4 * q4 + 3] = bb.w;
        }
        #pragma unroll
        for (int dr = -1; dr <= 1; ++dr) {
            int rr = rr0 + dr;
            if ((unsigned)rr >= 8u) continue;
            #pragma unroll
            for (int dss = -1; dss <= 1; ++dss) {
                int ss = ss0 + dss;
                if ((unsigned)ss >= 8u) continue;
                int pp = rr * 8 + ss;
                int tap = (dr + 1) * 3 + (dss + 1);
                const uint4v* ap = (const uint4v*)&buf1[pp * 104 + c0];
                uint4v av0 = ap[0], av1 = ap[1], av2 = ap[2];
                float wf[24];
                #pragma unroll
                for (int q4 = 0; q4 < 6; ++q4) {
                    float4 ww = *(const float4*)&lwT[tap * 96 + c0 + 4 * q4];
                    wf[4 * q4] = ww.x; wf[4 * q4 + 1] = ww.y;
                    wf[4 * q4 + 2] = ww.z; wf[4 * q4 + 3] = ww.w;
                }
                #pragma unroll
                for (int u = 0; u < 12; ++u) {
                    unsigned uu = (u < 4) ? av0[u] : (u < 8) ? av1[u - 4] : av2[u - 8];
                    lac[2 * u]     = fmaf(wf[2 * u],     lofp(uu), lac[2 * u]);
                    lac[2 * u + 1] = fmaf(wf[2 * u + 1], hifp(uu), lac[2 * u + 1]);
                }
            }
        }
        #pragma unroll
        for (int u = 0; u < 12; ++u) Lp[u] = pk_bf16(lac[2 * u], lac[2 * u + 1]);
    }
    __syncthreads();

    // ---- P1b: Q -> buf1 (in place), K -> buf2 (in place), V -> Vt ----
    {
        f32x4 qa[6];
        gemm_g(af_a, WtT, l15, quad, qa);
        #pragma unroll
        for (int nt = 0; nt < 6; ++nt) {
            int col = nt * 16 + l15;
            float bb = bq[col];
            #pragma unroll
            for (int r = 0; r < 4; ++r)
                buf1[(mt * 16 + quad * 4 + r) * 104 + col] = bfbits(qa[nt][r] + bb);
        }
    }
    __builtin_amdgcn_sched_barrier(0);
    {
        f32x4 ka[6];
        gemm_g(af_b, WtT + 9216, l15, quad, ka);
        #pragma unroll
        for (int nt = 0; nt < 6; ++nt) {
            int col = nt * 16 + l15;
            float bb = bk[col];
            #pragma unroll
            for (int r = 0; r < 4; ++r)
                buf2[(mt * 16 + quad * 4 + r) * 104 + col] = bfbits(ka[nt][r] + bb);
        }
    }
    __builtin_amdgcn_sched_barrier(0);
    {
        f32x4 va[6];
        gemm_g(af_b, WtT + 18432, l15, quad, va);
        #pragma unroll
        for (int nt = 0; nt < 6; ++nt) {
            float bb = bv[nt * 16 + l15];
            uint2v pk;
            pk[0] = pk_bf16(va[nt][0] + bb, va[nt][1] + bb);
            pk[1] = pk_bf16(va[nt][2] + bb, va[nt][3] + bb);
            *(uint2v*)&Vt[(nt * 16 + l15) * 72 + mt * 16 + quad * 4] = pk;
        }
    }
    __syncthreads();

    // ---- P2: S = QK^T, softmax in registers ----
    float pr[4][4], inv4[4];
    {
        short8 qf[3];
        #pragma unroll
        for (int ks = 0; ks < 3; ++ks)
            qf[ks] = *(const short8*)&buf1[arow + ks * 32 + quad * 8];
        f32x4 sa[4];
        #pragma unroll
        for (int nt = 0; nt < 4; ++nt) {
            f32x4 c = {0.f, 0.f, 0.f, 0.f};
            #pragma unroll
            for (int ks = 0; ks < 3; ++ks) {
                short8 bf = *(const short8*)&buf2[(nt * 16 + l15) * 104 + ks * 32 + quad * 8];
                c = __builtin_amdgcn_mfma_f32_16x16x32_bf16(qf[ks], bf, c, 0, 0, 0);
            }
            sa[nt] = c;
        }
        const float scale = 0.10206207261596575f;
        #pragma unroll
        for (int r = 0; r < 4; ++r) {
            float mx = fmaxf(fmaxf(sa[0][r], sa[1][r]), fmaxf(sa[2][r], sa[3][r]));
            #pragma unroll
            for (int d = 1; d < 16; d <<= 1) mx = fmaxf(mx, __shfl_xor(mx, d, 16));
            float sum = 0.f;
            #pragma unroll
            for (int nt = 0; nt < 4; ++nt) {
                float e = __expf((sa[nt][r] - mx) * scale);
                pr[r][nt] = e; sum += e;
            }
            #pragma unroll
            for (int d = 1; d < 16; d <<= 1) sum += __shfl_xor(sum, d, 16);
            inv4[r] = 1.f / sum;
        }
    }
    __syncthreads();   // last barrier: protects Ss/Ls overwrite of Qs/Ks

    // ---- P3: probs -> buf1 (over Qs), lepe -> buf2 (over Ks); own rows only
    #pragma unroll
    for (int r = 0; r < 4; ++r) {
        #pragma unroll
        for (int nt = 0; nt < 4; ++nt)
            buf1[(mt * 16 + quad * 4 + r) * 104 + nt * 16 + l15] =
                bfbits(pr[r][nt] * inv4[r]);
    }
    {
        uint4v* lp = (uint4v*)&buf2[arow + 24 * quad];
        uint4v l0 = {Lp[0], Lp[1], Lp[2], Lp[3]};
        uint4v l1 = {Lp[4], Lp[5], Lp[6], Lp[7]};
        uint4v l2 = {Lp[8], Lp[9], Lp[10], Lp[11]};
        lp[0] = l0; lp[1] = l1; lp[2] = l2;
    }

    // ---- P4: O = S @ V -> buf1 (over Ss); wave-local, no barrier ----
    {
        short8 sf[2];
        sf[0] = *(const short8*)&buf1[arow + quad * 8];
        sf[1] = *(const short8*)&buf1[arow + 32 + quad * 8];
        f32x4 oa[6];
        #pragma unroll
        for (int nt = 0; nt < 6; ++nt) {
            f32x4 c = {0.f, 0.f, 0.f, 0.f};
            #pragma unroll
            for (int ks = 0; ks < 2; ++ks) {
                short8 bf = *(const short8*)&Vt[(nt * 16 + l15) * 72 + ks * 32 + quad * 8];
                c = __builtin_amdgcn_mfma_f32_16x16x32_bf16(sf[ks], bf, c, 0, 0, 0);
            }
            oa[nt] = c;
        }
        #pragma unroll
        for (int nt = 0; nt < 6; ++nt)
            #pragma unroll
            for (int r = 0; r < 4; ++r)
                buf1[(mt * 16 + quad * 4 + r) * 104 + nt * 16 + l15] = bfbits(oa[nt][r]);
    }

    // ---- P6: out = (O + L) @ Wp + bp; wave-local, no barrier ----
    {
        short8 of[3], lf[3];
        #pragma unroll
        for (int ks = 0; ks < 3; ++ks) {
            of[ks] = *(const short8*)&buf1[arow + ks * 32 + quad * 8];
            lf[ks] = *(const short8*)&buf2[arow + ks * 32 + quad * 8];
        }
        const unsigned short* Wp_ = WtT + 27648;
        int b = n >> 10, ii = (n >> 5) & 31, jj = n & 31;
        // token index p2 = mt*16 + quad*4 + r; for fixed (mt,quad) the 4 r's
        // are consecutive floats: mt*512 + (quad>>1)*256 + (quad&1)*4 + r.
        size_t pbase = (size_t)(ii * 2048 + jj * 8 + mt * 512 +
                                (quad >> 1) * 256 + (quad & 1) * 4);
        #pragma unroll
        for (int nt = 0; nt < 6; ++nt) {
            f32x4 c = {0.f, 0.f, 0.f, 0.f};
            #pragma unroll
            for (int ks = 0; ks < 3; ++ks) {
                short8 bf = *(const short8*)&Wp_[(nt * 16 + l15) * 96 + ks * 32 + quad * 8];
                c = __builtin_amdgcn_mfma_f32_16x16x32_bf16(of[ks], bf, c, 0, 0, 0);
                c = __builtin_amdgcn_mfma_f32_16x16x32_bf16(lf[ks], bf, c, 0, 0, 0);
            }
            int co = nt * 16 + l15;
            float bb = bp[co];
            float4 st;
            st.x = c[0] + bb; st.y = c[1] + bb; st.z = c[2] + bb; st.w = c[3] + bb;
            *(float4*)&out[(((size_t)(b * 96 + co)) << 16) + pbase] = st;
        }
    }
}

// ---------------------------------------------------------------------------
extern "C" void kernel_launch(void* const* d_in, const int* in_sizes, int n_in,
                              void* d_out, int out_size, void* d_ws, size_t ws_size,
                              hipStream_t stream)
{
    (void)in_sizes; (void)n_in; (void)out_size;
    const float* x  = (const float*)d_in[0];
    const float* Wq = (const float*)d_in[1];
    const float* bq = (const float*)d_in[2];
    const float* Wk = (const float*)d_in[3];
    const float* bk = (const float*)d_in[4];
    const float* Wv = (const float*)d_in[5];
    const float* bv = (const float*)d_in[6];
    const float* Wp = (const float*)d_in[7];
    const float* bp = (const float*)d_in[8];
    const float* lw = (const float*)d_in[9];
    const float* lb = (const float*)d_in[10];
    float* out = (float*)d_out;

    char* ws = (char*)d_ws;
    float* dsxT = (float*)ws;                               // 1,572,864 B
    float* pv   = (float*)(ws + 1572864);                   //   786,432 B
    int*   pi   = (int*)  (ws + 2359296);                   //   786,432 B
    float* w3   = (float*)(ws + 3145728);                   //    49,152 B
    int*   i3   = (int*)  (ws + 3194880);                   //    49,152 B
    unsigned short* WtT = (unsigned short*)(ws + 3244032);  //    73,728 B
    float* lwT  = (float*)(ws + 3317760);                   //     3,456 B
    unsigned short* xwg = (unsigned short*)(ws + 3321344);  // 50,331,648 B
    bool use_xwg = (ws_size >= 53652992ull);

    (void)hipFuncSetAttribute(reinterpret_cast<const void*>(&k_attn<true>),
                        hipFuncAttributeMaxDynamicSharedMemorySize, 40448);
    (void)hipFuncSetAttribute(reinterpret_cast<const void*>(&k_attn<false>),
                        hipFuncAttributeMaxDynamicSharedMemorySize, 40448);

    k_prep<<<22, 256, 0, stream>>>(Wq, Wk, Wv, Wp, lw, WtT, lwT);
    if (use_xwg) {
        k_cast<<<4096, 768, 0, stream>>>(x, xwg, dsxT);
    } else {
        k_pool<<<1536, 256, 0, stream>>>(x, dsxT);
    }
    k_sim<<<512, 256, 0, stream>>>(dsxT, pv, pi);
    k_topk<<<16, 256, 0, stream>>>(pv, pi, w3, i3);
    if (use_xwg) {
        k_attn<true><<<4096, 256, 40448, stream>>>(x, xwg, WtT, lwT, bq, bk, bv, bp,
                                                   lb, w3, i3, out);
    } else {
        k_attn<false><<<4096, 256, 40448, stream>>>(x, nullptr, WtT, lwT, bq, bk, bv, bp,
                                                    lb, w3, i3, out);
    }
}

// Round 4
// 428.366 us; speedup vs baseline: 1.0821x; 1.0483x over previous
//
#include <hip/hip_runtime.h>

typedef __attribute__((ext_vector_type(8))) short  short8;
typedef __attribute__((ext_vector_type(4))) float  f32x4;
typedef __attribute__((ext_vector_type(4))) unsigned int uint4v;
typedef __attribute__((ext_vector_type(2))) unsigned int uint2v;

#define NEG_INF (-3.402823466e38f)

__device__ __forceinline__ unsigned short bfbits(float f) {
    unsigned u = __builtin_bit_cast(unsigned, f);
    u += 0x7fffu + ((u >> 16) & 1u);
    return (unsigned short)(u >> 16);
}
__device__ __forceinline__ unsigned pk_bf16(float lo, float hi) {
    return (unsigned)bfbits(lo) | ((unsigned)bfbits(hi) << 16);
}
__device__ __forceinline__ float lofp(unsigned u) {
    return __builtin_bit_cast(float, u << 16);
}
__device__ __forceinline__ float hifp(unsigned u) {
    return __builtin_bit_cast(float, u & 0xffff0000u);
}
__device__ __forceinline__ float bf2f(short x) {
    return __builtin_bit_cast(float, ((unsigned)(unsigned short)x) << 16);
}

__device__ __forceinline__ void ins3(float (&tv)[3], int (&ti)[3], float v, int ci)
{
    if (v > tv[0] || (v == tv[0] && ci < ti[0])) {
        tv[2] = tv[1]; ti[2] = ti[1];
        tv[1] = tv[0]; ti[1] = ti[0];
        tv[0] = v;     ti[0] = ci;
    } else if (v > tv[1] || (v == tv[1] && ci < ti[1])) {
        tv[2] = tv[1]; ti[2] = ti[1];
        tv[1] = v;     ti[1] = ci;
    } else if (v > tv[2] || (v == tv[2] && ci < ti[2])) {
        tv[2] = v;     ti[2] = ci;
    }
}

// -------- Kernel 1 (fallback only): maxpool fp32 ----------------------------
__global__ __launch_bounds__(256) void k_pool(const float* __restrict__ x,
                                              float* __restrict__ dsxT)
{
    int gid = blockIdx.x * 256 + threadIdx.x;
    int c = gid >> 12;
    int n = gid & 4095;
    int b = n >> 10, i = (n >> 5) & 31, j = n & 31;
    const float* p = x + (((size_t)(b * 96 + c)) << 16) + i * 2048 + j * 8;
    float4 m0 = *(const float4*)p;
    float4 m1 = *(const float4*)(p + 4);
    #pragma unroll
    for (int r = 1; r < 8; ++r) {
        float4 a0 = *(const float4*)(p + r * 256);
        float4 a1 = *(const float4*)(p + r * 256 + 4);
        m0.x = fmaxf(m0.x, a0.x); m0.y = fmaxf(m0.y, a0.y);
        m0.z = fmaxf(m0.z, a0.z); m0.w = fmaxf(m0.w, a0.w);
        m1.x = fmaxf(m1.x, a1.x); m1.y = fmaxf(m1.y, a1.y);
        m1.z = fmaxf(m1.z, a1.z); m1.w = fmaxf(m1.w, a1.w);
    }
    float m = fmaxf(fmaxf(fmaxf(m0.x, m0.y), fmaxf(m0.z, m0.w)),
                    fmaxf(fmaxf(m1.x, m1.y), fmaxf(m1.z, m1.w)));
    dsxT[c * 4096 + n] = m;
}

// -------- Kernel 0b: x -> xwg bf16 + pooled maxima as 3-way bf16 split ------
// hi/mid/lo planes give ~24 mantissa bits; residual 2^-24 relative.
__global__ __launch_bounds__(768) void k_cast(const float* __restrict__ x,
                                              unsigned short* __restrict__ xwg,
                                              unsigned short* __restrict__ dsxH,
                                              unsigned short* __restrict__ dsxM,
                                              unsigned short* __restrict__ dsxL)
{
    // XCD swizzle: contiguous 512-window chunk per XCD for 64B-line sharing
    int n = ((blockIdx.x & 7) << 9) | (blockIdx.x >> 3);
    int t = threadIdx.x;
    int cg = t >> 6, p = t & 63;                 // wave == one cg (8 channels)
    int b = n >> 10, i = (n >> 5) & 31, j = n & 31;
    int h = i * 8 + (p >> 3), w = j * 8 + (p & 7);
    size_t base = (((size_t)(b * 96 + 8 * cg)) << 16) + (size_t)(h * 256 + w);
    float v[8];
    #pragma unroll
    for (int jj = 0; jj < 8; ++jj) v[jj] = x[base + (((size_t)jj) << 16)];
    uint4v pk;
    #pragma unroll
    for (int jj = 0; jj < 4; ++jj) pk[jj] = pk_bf16(v[2 * jj], v[2 * jj + 1]);
    *(uint4v*)&xwg[(size_t)n * 6144 + p * 96 + 8 * cg] = pk;
    // window max per channel via full-wave shuffle reduce; 3-way bf16 split
    #pragma unroll
    for (int jj = 0; jj < 8; ++jj) {
        float m = v[jj];
        #pragma unroll
        for (int d = 1; d < 64; d <<= 1) m = fmaxf(m, __shfl_xor(m, d, 64));
        if (p == 0) {
            unsigned short hb = bfbits(m);
            float r1 = m - __builtin_bit_cast(float, ((unsigned)hb) << 16);
            unsigned short mb = bfbits(r1);
            float r2 = r1 - __builtin_bit_cast(float, ((unsigned)mb) << 16);
            dsxH[n * 96 + 8 * cg + jj] = hb;
            dsxM[n * 96 + 8 * cg + jj] = mb;
            dsxL[n * 96 + 8 * cg + jj] = bfbits(r2);
        }
    }
}

// -------- Kernel 2 (fallback): similarity + partial top3, fp32 VALU ---------
__global__ __launch_bounds__(256) void k_sim(const float* __restrict__ dsxT,
                                             float* __restrict__ pv,
                                             int* __restrict__ pi)
{
    __shared__ __align__(16) float qt[32 * 128];   // 16384 B
    __shared__ __align__(16) float ct[32 * 144];   // 18432 B (pad 4 per 32)
    int t = threadIdx.x;
    int qti = blockIdx.x >> 4;
    int ch  = blockIdx.x & 15;
    int ty = t >> 4, tx = t & 15;
    int qb = qti * 128;

    float tv[8][3]; int ti[8][3];
    #pragma unroll
    for (int a = 0; a < 8; ++a)
        #pragma unroll
        for (int k = 0; k < 3; ++k) { tv[a][k] = NEG_INF; ti[a][k] = 0x7fffffff; }

    #pragma unroll
    for (int pass = 0; pass < 2; ++pass) {
        int cb = ch * 256 + pass * 128;
        float acc[8][8];
        #pragma unroll
        for (int a = 0; a < 8; ++a)
            #pragma unroll
            for (int e = 0; e < 8; ++e) acc[a][e] = 0.f;

        for (int kc = 0; kc < 3; ++kc) {
            __syncthreads();
            #pragma unroll
            for (int f4 = 0; f4 < 4; ++f4) {
                int f = t + f4 * 256;             // 0..1023
                int kk = f >> 5, cq = f & 31;
                *(float4*)&qt[kk * 128 + 4 * cq] =
                    *(const float4*)&dsxT[(kc * 32 + kk) * 4096 + qb + 4 * cq];
                *(float4*)&ct[kk * 144 + 4 * cq + 4 * (cq >> 3)] =
                    *(const float4*)&dsxT[(kc * 32 + kk) * 4096 + cb + 4 * cq];
            }
            __syncthreads();
            #pragma unroll 2
            for (int kk = 0; kk < 32; ++kk) {
                float4 q0 = *(float4*)&qt[kk * 128 + 8 * ty];
                float4 q1 = *(float4*)&qt[kk * 128 + 8 * ty + 4];
                int e0 = 8 * tx, e1 = 8 * tx + 4;
                float4 c0 = *(float4*)&ct[kk * 144 + e0 + 4 * (e0 >> 5)];
                float4 c1 = *(float4*)&ct[kk * 144 + e1 + 4 * (e1 >> 5)];
                float qv[8] = {q0.x, q0.y, q0.z, q0.w, q1.x, q1.y, q1.z, q1.w};
                float cv[8] = {c0.x, c0.y, c0.z, c0.w, c1.x, c1.y, c1.z, c1.w};
                #pragma unroll
                for (int a = 0; a < 8; ++a)
                    #pragma unroll
                    for (int e = 0; e < 8; ++e)
                        acc[a][e] = fmaf(qv[a], cv[e], acc[a][e]);
            }
        }
        #pragma unroll
        for (int e = 0; e < 8; ++e) {
            int ci = cb + 8 * tx + e;
            #pragma unroll
            for (int a = 0; a < 8; ++a) ins3(tv[a], ti[a], acc[a][e], ci);
        }
    }

    #pragma unroll
    for (int d = 1; d < 16; d <<= 1) {
        #pragma unroll
        for (int a = 0; a < 8; ++a) {
            float ov[3]; int oi[3];
            #pragma unroll
            for (int k = 0; k < 3; ++k) {
                ov[k] = __shfl_xor(tv[a][k], d, 16);
                oi[k] = __shfl_xor(ti[a][k], d, 16);
            }
            #pragma unroll
            for (int k = 0; k < 3; ++k) ins3(tv[a], ti[a], ov[k], oi[k]);
        }
    }
    if (tx == 0) {
        #pragma unroll
        for (int a = 0; a < 8; ++a) {
            int nq = qti * 128 + 8 * ty + a;
            #pragma unroll
            for (int k = 0; k < 3; ++k) {
                pv[nq * 48 + ch * 3 + k] = tv[a][k];
                pi[nq * 48 + ch * 3 + k] = ti[a][k];
            }
        }
    }
}

// -------- Kernel 2m (primary): candidate top-3 via 3-split bf16 MFMA --------
// sim ~= HH + (HM+MH+MM+HL+LH); corrections accumulate in a separate small
// accumulator to avoid ULP(460) rounding per step. Score noise ~1e-4 (fp32
// class). Emits candidate INDICES only; exact fp32 rescore happens in k_top3x.
__global__ __launch_bounds__(256) void k_sim_bf(const unsigned short* __restrict__ dsxH,
                                                const unsigned short* __restrict__ dsxM,
                                                const unsigned short* __restrict__ dsxL,
                                                int* __restrict__ pi)
{
    int t = threadIdx.x;
    int qti = blockIdx.x >> 4;
    int ch  = blockIdx.x & 15;
    int lane = t & 63, wv = t >> 6;
    int l15 = lane & 15, quad = lane >> 4;
    int cb = ch * 256;

    #pragma unroll
    for (int a2 = 0; a2 < 2; ++a2) {
        int at = wv * 2 + a2;
        int qrow = qti * 128 + at * 16 + l15;
        short8 aH[3], aM[3], aL[3];
        #pragma unroll
        for (int ks = 0; ks < 3; ++ks) {
            aH[ks] = *(const short8*)&dsxH[qrow * 96 + ks * 32 + quad * 8];
            aM[ks] = *(const short8*)&dsxM[qrow * 96 + ks * 32 + quad * 8];
            aL[ks] = *(const short8*)&dsxL[qrow * 96 + ks * 32 + quad * 8];
        }
        float tv[4][3]; int ti[4][3];
        #pragma unroll
        for (int r = 0; r < 4; ++r)
            #pragma unroll
            for (int k = 0; k < 3; ++k) { tv[r][k] = NEG_INF; ti[r][k] = 0x7fffffff; }

        for (int bt = 0; bt < 16; ++bt) {
            int crow = cb + bt * 16 + l15;
            f32x4 c  = {0.f, 0.f, 0.f, 0.f};
            f32x4 c2 = {0.f, 0.f, 0.f, 0.f};
            #pragma unroll
            for (int ks = 0; ks < 3; ++ks) {
                short8 bH = *(const short8*)&dsxH[crow * 96 + ks * 32 + quad * 8];
                short8 bM = *(const short8*)&dsxM[crow * 96 + ks * 32 + quad * 8];
                short8 bL = *(const short8*)&dsxL[crow * 96 + ks * 32 + quad * 8];
                c  = __builtin_amdgcn_mfma_f32_16x16x32_bf16(aH[ks], bH, c,  0, 0, 0);
                c2 = __builtin_amdgcn_mfma_f32_16x16x32_bf16(aH[ks], bM, c2, 0, 0, 0);
                c2 = __builtin_amdgcn_mfma_f32_16x16x32_bf16(aM[ks], bH, c2, 0, 0, 0);
                c2 = __builtin_amdgcn_mfma_f32_16x16x32_bf16(aM[ks], bM, c2, 0, 0, 0);
                c2 = __builtin_amdgcn_mfma_f32_16x16x32_bf16(aH[ks], bL, c2, 0, 0, 0);
                c2 = __builtin_amdgcn_mfma_f32_16x16x32_bf16(aL[ks], bH, c2, 0, 0, 0);
            }
            #pragma unroll
            for (int r = 0; r < 4; ++r)
                ins3(tv[r], ti[r], c[r] + c2[r], cb + bt * 16 + l15);
        }
        #pragma unroll
        for (int d = 1; d < 16; d <<= 1) {
            #pragma unroll
            for (int r = 0; r < 4; ++r) {
                float ov[3]; int oi[3];
                #pragma unroll
                for (int k = 0; k < 3; ++k) {
                    ov[k] = __shfl_xor(tv[r][k], d, 16);
                    oi[k] = __shfl_xor(ti[r][k], d, 16);
                }
                #pragma unroll
                for (int k = 0; k < 3; ++k) ins3(tv[r], ti[r], ov[k], oi[k]);
            }
        }
        if (l15 == 0) {
            #pragma unroll
            for (int r = 0; r < 4; ++r) {
                int nq = qti * 128 + at * 16 + quad * 4 + r;
                #pragma unroll
                for (int k = 0; k < 3; ++k)
                    pi[nq * 48 + ch * 3 + k] = ti[r][k];
            }
        }
    }
}

// -------- Kernel 2x (primary): exact fp32 rescore of 48 candidates ----------
// One wave per window; lane j rescores candidate j with fp32-reconstructed
// values (H+M+L, residual 2^-24) in a fixed sequential order, then a 64-lane
// butterfly top-3 with lower-index tie-break (matches jax top_k semantics).
__global__ __launch_bounds__(256) void k_top3x(const unsigned short* __restrict__ dsxH,
                                               const unsigned short* __restrict__ dsxM,
                                               const unsigned short* __restrict__ dsxL,
                                               const int* __restrict__ pi,
                                               float* __restrict__ w3,
                                               int* __restrict__ i3)
{
    int t = threadIdx.x;
    int lane = t & 63, wv = t >> 6;
    int n = blockIdx.x * 4 + wv;
    int cand = (lane < 48) ? pi[n * 48 + lane] : 0;
    float s = 0.f;
    #pragma unroll
    for (int ck = 0; ck < 12; ++ck) {
        short8 qh = *(const short8*)&dsxH[n * 96 + ck * 8];
        short8 qm = *(const short8*)&dsxM[n * 96 + ck * 8];
        short8 ql = *(const short8*)&dsxL[n * 96 + ck * 8];
        short8 kh = *(const short8*)&dsxH[cand * 96 + ck * 8];
        short8 km = *(const short8*)&dsxM[cand * 96 + ck * 8];
        short8 kl = *(const short8*)&dsxL[cand * 96 + ck * 8];
        #pragma unroll
        for (int e = 0; e < 8; ++e) {
            float qv = (bf2f(qh[e]) + bf2f(qm[e])) + bf2f(ql[e]);
            float kv = (bf2f(kh[e]) + bf2f(km[e])) + bf2f(kl[e]);
            s = fmaf(qv, kv, s);
        }
    }
    float tv[3] = {NEG_INF, NEG_INF, NEG_INF};
    int   ti[3] = {0x7fffffff, 0x7fffffff, 0x7fffffff};
    if (lane < 48) { tv[0] = s; ti[0] = cand; }
    #pragma unroll
    for (int d = 1; d < 64; d <<= 1) {
        float ov[3]; int oi[3];
        #pragma unroll
        for (int k = 0; k < 3; ++k) {
            ov[k] = __shfl_xor(tv[k], d, 64);
            oi[k] = __shfl_xor(ti[k], d, 64);
        }
        #pragma unroll
        for (int k = 0; k < 3; ++k) ins3(tv, ti, ov[k], oi[k]);
    }
    if (lane == 0) {
        float e1 = expf(tv[1] - tv[0]);
        float e2 = expf(tv[2] - tv[0]);
        float inv = 1.f / (1.f + e1 + e2);
        w3[n * 3 + 0] = inv;
        w3[n * 3 + 1] = e1 * inv;
        w3[n * 3 + 2] = e2 * inv;
        i3[n * 3 + 0] = ti[0];
        i3[n * 3 + 1] = ti[1];
        i3[n * 3 + 2] = ti[2];
    }
}

// ---------------- Kernel 2b (fallback): final top3 merge + softmax ----------
__global__ __launch_bounds__(256) void k_topk(const float* __restrict__ pv,
                                              const int* __restrict__ pi,
                                              float* __restrict__ w3,
                                              int* __restrict__ i3)
{
    int n = blockIdx.x * 256 + threadIdx.x;
    float bv[3] = {NEG_INF, NEG_INF, NEG_INF};
    int   bi[3] = {0x7fffffff, 0x7fffffff, 0x7fffffff};
    for (int e = 0; e < 48; ++e)
        ins3(bv, bi, pv[n * 48 + e], pi[n * 48 + e]);
    float e1 = expf(bv[1] - bv[0]);
    float e2 = expf(bv[2] - bv[0]);
    float inv = 1.f / (1.f + e1 + e2);
    w3[n * 3 + 0] = inv;
    w3[n * 3 + 1] = e1 * inv;
    w3[n * 3 + 2] = e2 * inv;
    i3[n * 3 + 0] = bi[0];
    i3[n * 3 + 1] = bi[1];
    i3[n * 3 + 2] = bi[2];
}

// -------- Kernel 0a: weights -> WtT[4][96co][96ci] bf16 ; lwT[9][96] fp32 ---
__global__ __launch_bounds__(256) void k_prep(const float* __restrict__ Wq,
                                              const float* __restrict__ Wk,
                                              const float* __restrict__ Wv,
                                              const float* __restrict__ Wp,
                                              const float* __restrict__ lw,
                                              unsigned short* __restrict__ WtT,
                                              float* __restrict__ lwT)
{
    int g = blockIdx.x * 256 + threadIdx.x;
    if (g < 4608) {
        int w  = g / 1152;
        int co = (g % 1152) / 12;
        int cg = g % 12;
        const float* src = (w == 0) ? Wq : (w == 1) ? Wk : (w == 2) ? Wv : Wp;
        unsigned short* dst = WtT + w * 9216 + co * 96 + 8 * cg;
        #pragma unroll
        for (int j = 0; j < 8; ++j) dst[j] = bfbits(src[(8 * cg + j) * 96 + co]);
    } else if (g < 5472) {
        int i2 = g - 4608;
        int tap = i2 / 96, c = i2 % 96;
        lwT[tap * 96 + c] = lw[c * 9 + tap];
    }
}

// ----------------------- Kernel 3: fused MFMA window attention --------------
__device__ __forceinline__ size_t win_off(int m)
{
    return (((size_t)(m >> 10) * 96) << 16) +
           (size_t)(((m >> 5) & 31) * 2048 + (m & 31) * 8);
}

__device__ __forceinline__ void gemm_g(const short8* af,
                                       const unsigned short* __restrict__ Wt,
                                       int l15, int quad, f32x4* acc)
{
    #pragma unroll
    for (int nt = 0; nt < 6; ++nt) {
        f32x4 c = {0.f, 0.f, 0.f, 0.f};
        #pragma unroll
        for (int ks = 0; ks < 3; ++ks) {
            short8 bf = *(const short8*)&Wt[(nt * 16 + l15) * 96 + ks * 32 + quad * 8];
            c = __builtin_amdgcn_mfma_f32_16x16x32_bf16(af[ks], bf, c, 0, 0, 0);
        }
        acc[nt] = c;
    }
}

template<bool XWG>
__global__ __attribute__((amdgpu_waves_per_eu(4, 4)))
__launch_bounds__(256) void k_attn(
    const float* __restrict__ x,
    const unsigned short* __restrict__ xwg,
    const unsigned short* __restrict__ WtT,
    const float* __restrict__ lwT,
    const float* __restrict__ bq, const float* __restrict__ bk,
    const float* __restrict__ bv, const float* __restrict__ bp,
    const float* __restrict__ lb,
    const float* __restrict__ w3, const int* __restrict__ i3,
    float* __restrict__ out)
{
    extern __shared__ __align__(16) unsigned short sm[];
    unsigned short* buf1 = sm;            // 6656 shorts
    unsigned short* buf2 = sm + 6656;     // 6656 shorts
    unsigned short* Vt   = sm + 13312;    // 6912 shorts

    int t = threadIdx.x;
    int n = ((blockIdx.x & 7) << 9) | (blockIdx.x >> 3);
    int lane = t & 63, mt = t >> 6;
    int l15 = lane & 15, quad = lane >> 4;

    float wk0 = w3[n * 3 + 0], wk1 = w3[n * 3 + 1], wk2 = w3[n * 3 + 2];
    int   m0  = i3[n * 3 + 0], m1 = i3[n * 3 + 1], m2 = i3[n * 3 + 2];

    if (XWG) {
        #pragma unroll
        for (int it = 0; it < 3; ++it) {
            int g = it * 256 + t;
            int p = g / 12, cg = g % 12;
            int o = p * 96 + 8 * cg;
            uint4v sv = *(const uint4v*)&xwg[(size_t)n * 6144 + o];
            *(uint4v*)&buf1[p * 104 + 8 * cg] = sv;
            uint4v a0 = *(const uint4v*)&xwg[(size_t)m0 * 6144 + o];
            uint4v a1 = *(const uint4v*)&xwg[(size_t)m1 * 6144 + o];
            uint4v a2 = *(const uint4v*)&xwg[(size_t)m2 * 6144 + o];
            uint4v rs;
            #pragma unroll
            for (int e = 0; e < 4; ++e) {
                float lo = wk0 * lofp(a0[e]) + wk1 * lofp(a1[e]) + wk2 * lofp(a2[e]);
                float hi = wk0 * hifp(a0[e]) + wk1 * hifp(a1[e]) + wk2 * hifp(a2[e]);
                rs[e] = pk_bf16(lo, hi);
            }
            *(uint4v*)&buf2[p * 104 + 8 * cg] = rs;
        }
    } else {
        size_t so = win_off(n), o0 = win_off(m0), o1 = win_off(m1), o2 = win_off(m2);
        #pragma unroll
        for (int it = 0; it < 3; ++it) {
            int g = it * 256 + t;
            int p = g / 12, cg = g % 12;
            size_t po = (size_t)((p >> 3) * 256 + (p & 7));
            uint4v ra, rb;
            #pragma unroll
            for (int jj = 0; jj < 4; ++jj) {
                size_t clo = (((size_t)(8 * cg + 2 * jj)) << 16) + po;
                size_t chi = clo + ((size_t)1 << 16);
                ra[jj] = pk_bf16(x[so + clo], x[so + chi]);
                float blo = wk0 * x[o0 + clo] + wk1 * x[o1 + clo] + wk2 * x[o2 + clo];
                float bhi = wk0 * x[o0 + chi] + wk1 * x[o1 + chi] + wk2 * x[o2 + chi];
                rb[jj] = pk_bf16(blo, bhi);
            }
            *(uint4v*)&buf1[p * 104 + 8 * cg] = ra;
            *(uint4v*)&buf2[p * 104 + 8 * cg] = rb;
        }
    }
    __syncthreads();

    short8 af_a[3], af_b[3];
    int arow = (mt * 16 + l15) * 104;
    #pragma unroll
    for (int ks = 0; ks < 3; ++ks) {
        af_a[ks] = *(const short8*)&buf1[arow + ks * 32 + quad * 8];
        af_b[ks] = *(const short8*)&buf2[arow + ks * 32 + quad * 8];
    }
    unsigned Lp[12];
    {
        int rowp = mt * 16 + l15;
        int c0 = 24 * quad;
        int rr0 = rowp >> 3, ss0 = rowp & 7;
        float lac[24];
        #pragma unroll
        for (int q4 = 0; q4 < 6; ++q4) {
            float4 bb = *(const float4*)&lb[c0 + 4 * q4];
            lac[4 * q4] = bb.x; lac[4 * q4 + 1] = bb.y;
            lac[4 * q4 + 2] = bb.z; lac[4 * q4 + 3] = bb.w;
        }
        #pragma unroll
        for (int dr = -1; dr <= 1; ++dr) {
            int rr = rr0 + dr;
            if ((unsigned)rr >= 8u) continue;
            #pragma unroll
            for (int dss = -1; dss <= 1; ++dss) {
                int ss = ss0 + dss;
                if ((unsigned)ss >= 8u) continue;
                int pp = rr * 8 + ss;
                int tap = (dr + 1) * 3 + (dss + 1);
                const uint4v* ap = (const uint4v*)&buf1[pp * 104 + c0];
                uint4v av0 = ap[0], av1 = ap[1], av2 = ap[2];
                float wf[24];
                #pragma unroll
                for (int q4 = 0; q4 < 6; ++q4) {
                    float4 ww = *(const float4*)&lwT[tap * 96 + c0 + 4 * q4];
                    wf[4 * q4] = ww.x; wf[4 * q4 + 1] = ww.y;
                    wf[4 * q4 + 2] = ww.z; wf[4 * q4 + 3] = ww.w;
                }
                #pragma unroll
                for (int u = 0; u < 12; ++u) {
                    unsigned uu = (u < 4) ? av0[u] : (u < 8) ? av1[u - 4] : av2[u - 8];
                    lac[2 * u]     = fmaf(wf[2 * u],     lofp(uu), lac[2 * u]);
                    lac[2 * u + 1] = fmaf(wf[2 * u + 1], hifp(uu), lac[2 * u + 1]);
                }
            }
        }
        #pragma unroll
        for (int u = 0; u < 12; ++u) Lp[u] = pk_bf16(lac[2 * u], lac[2 * u + 1]);
    }
    __syncthreads();

    {
        f32x4 qa[6];
        gemm_g(af_a, WtT, l15, quad, qa);
        #pragma unroll
        for (int nt = 0; nt < 6; ++nt) {
            int col = nt * 16 + l15;
            float bb = bq[col];
            #pragma unroll
            for (int r = 0; r < 4; ++r)
                buf1[(mt * 16 + quad * 4 + r) * 104 + col] = bfbits(qa[nt][r] + bb);
        }
    }
    __builtin_amdgcn_sched_barrier(0);
    {
        f32x4 ka[6];
        gemm_g(af_b, WtT + 9216, l15, quad, ka);
        #pragma unroll
        for (int nt = 0; nt < 6; ++nt) {
            int col = nt * 16 + l15;
            float bb = bk[col];
            #pragma unroll
            for (int r = 0; r < 4; ++r)
                buf2[(mt * 16 + quad * 4 + r) * 104 + col] = bfbits(ka[nt][r] + bb);
        }
    }
    __builtin_amdgcn_sched_barrier(0);
    {
        f32x4 va[6];
        gemm_g(af_b, WtT + 18432, l15, quad, va);
        #pragma unroll
        for (int nt = 0; nt < 6; ++nt) {
            float bb = bv[nt * 16 + l15];
            uint2v pk;
            pk[0] = pk_bf16(va[nt][0] + bb, va[nt][1] + bb);
            pk[1] = pk_bf16(va[nt][2] + bb, va[nt][3] + bb);
            *(uint2v*)&Vt[(nt * 16 + l15) * 72 + mt * 16 + quad * 4] = pk;
        }
    }
    __syncthreads();

    float pr[4][4], inv4[4];
    {
        short8 qf[3];
        #pragma unroll
        for (int ks = 0; ks < 3; ++ks)
            qf[ks] = *(const short8*)&buf1[arow + ks * 32 + quad * 8];
        f32x4 sa[4];
        #pragma unroll
        for (int nt = 0; nt < 4; ++nt) {
            f32x4 c = {0.f, 0.f, 0.f, 0.f};
            #pragma unroll
            for (int ks = 0; ks < 3; ++ks) {
                short8 bf = *(const short8*)&buf2[(nt * 16 + l15) * 104 + ks * 32 + quad * 8];
                c = __builtin_amdgcn_mfma_f32_16x16x32_bf16(qf[ks], bf, c, 0, 0, 0);
            }
            sa[nt] = c;
        }
        const float scale = 0.10206207261596575f;
        #pragma unroll
        for (int r = 0; r < 4; ++r) {
            float mx = fmaxf(fmaxf(sa[0][r], sa[1][r]), fmaxf(sa[2][r], sa[3][r]));
            #pragma unroll
            for (int d = 1; d < 16; d <<= 1) mx = fmaxf(mx, __shfl_xor(mx, d, 16));
            float sum = 0.f;
            #pragma unroll
            for (int nt = 0; nt < 4; ++nt) {
                float e = __expf((sa[nt][r] - mx) * scale);
                pr[r][nt] = e; sum += e;
            }
            #pragma unroll
            for (int d = 1; d < 16; d <<= 1) sum += __shfl_xor(sum, d, 16);
            inv4[r] = 1.f / sum;
        }
    }
    __syncthreads();

    #pragma unroll
    for (int r = 0; r < 4; ++r) {
        #pragma unroll
        for (int nt = 0; nt < 4; ++nt)
            buf1[(mt * 16 + quad * 4 + r) * 104 + nt * 16 + l15] =
                bfbits(pr[r][nt] * inv4[r]);
    }
    {
        uint4v* lp = (uint4v*)&buf2[arow + 24 * quad];
        uint4v l0 = {Lp[0], Lp[1], Lp[2], Lp[3]};
        uint4v l1 = {Lp[4], Lp[5], Lp[6], Lp[7]};
        uint4v l2 = {Lp[8], Lp[9], Lp[10], Lp[11]};
        lp[0] = l0; lp[1] = l1; lp[2] = l2;
    }

    {
        short8 sf[2];
        sf[0] = *(const short8*)&buf1[arow + quad * 8];
        sf[1] = *(const short8*)&buf1[arow + 32 + quad * 8];
        f32x4 oa[6];
        #pragma unroll
        for (int nt = 0; nt < 6; ++nt) {
            f32x4 c = {0.f, 0.f, 0.f, 0.f};
            #pragma unroll
            for (int ks = 0; ks < 2; ++ks) {
                short8 bf = *(const short8*)&Vt[(nt * 16 + l15) * 72 + ks * 32 + quad * 8];
                c = __builtin_amdgcn_mfma_f32_16x16x32_bf16(sf[ks], bf, c, 0, 0, 0);
            }
            oa[nt] = c;
        }
        #pragma unroll
        for (int nt = 0; nt < 6; ++nt)
            #pragma unroll
            for (int r = 0; r < 4; ++r)
                buf1[(mt * 16 + quad * 4 + r) * 104 + nt * 16 + l15] = bfbits(oa[nt][r]);
    }

    {
        short8 of[3], lf[3];
        #pragma unroll
        for (int ks = 0; ks < 3; ++ks) {
            of[ks] = *(const short8*)&buf1[arow + ks * 32 + quad * 8];
            lf[ks] = *(const short8*)&buf2[arow + ks * 32 + quad * 8];
        }
        const unsigned short* Wp_ = WtT + 27648;
        int b = n >> 10, ii = (n >> 5) & 31, jj = n & 31;
        size_t pbase = (size_t)(ii * 2048 + jj * 8 + mt * 512 +
                                (quad >> 1) * 256 + (quad & 1) * 4);
        #pragma unroll
        for (int nt = 0; nt < 6; ++nt) {
            f32x4 c = {0.f, 0.f, 0.f, 0.f};
            #pragma unroll
            for (int ks = 0; ks < 3; ++ks) {
                short8 bf = *(const short8*)&Wp_[(nt * 16 + l15) * 96 + ks * 32 + quad * 8];
                c = __builtin_amdgcn_mfma_f32_16x16x32_bf16(of[ks], bf, c, 0, 0, 0);
                c = __builtin_amdgcn_mfma_f32_16x16x32_bf16(lf[ks], bf, c, 0, 0, 0);
            }
            int co = nt * 16 + l15;
            float bb = bp[co];
            float4 st;
            st.x = c[0] + bb; st.y = c[1] + bb; st.z = c[2] + bb; st.w = c[3] + bb;
            *(float4*)&out[(((size_t)(b * 96 + co)) << 16) + pbase] = st;
        }
    }
}

// ---------------------------------------------------------------------------
extern "C" void kernel_launch(void* const* d_in, const int* in_sizes, int n_in,
                              void* d_out, int out_size, void* d_ws, size_t ws_size,
                              hipStream_t stream)
{
    (void)in_sizes; (void)n_in; (void)out_size;
    const float* x  = (const float*)d_in[0];
    const float* Wq = (const float*)d_in[1];
    const float* bq = (const float*)d_in[2];
    const float* Wk = (const float*)d_in[3];
    const float* bk = (const float*)d_in[4];
    const float* Wv = (const float*)d_in[5];
    const float* bv = (const float*)d_in[6];
    const float* Wp = (const float*)d_in[7];
    const float* bp = (const float*)d_in[8];
    const float* lw = (const float*)d_in[9];
    const float* lb = (const float*)d_in[10];
    float* out = (float*)d_out;

    char* ws = (char*)d_ws;
    float* dsxT = (float*)ws;                               // 1,572,864 B (fallback)
    unsigned short* dsxH = (unsigned short*)ws;             //   786,432 B (primary)
    unsigned short* dsxM = (unsigned short*)(ws + 786432);  //   786,432 B (primary)
    unsigned short* dsxL = (unsigned short*)(ws + 1572864); //   786,432 B (primary; aliases pv)
    float* pv   = (float*)(ws + 1572864);                   //   786,432 B (fallback)
    int*   pi   = (int*)  (ws + 2359296);                   //   786,432 B
    float* w3   = (float*)(ws + 3145728);                   //    49,152 B
    int*   i3   = (int*)  (ws + 3194880);                   //    49,152 B
    unsigned short* WtT = (unsigned short*)(ws + 3244032);  //    73,728 B
    float* lwT  = (float*)(ws + 3317760);                   //     3,456 B
    unsigned short* xwg = (unsigned short*)(ws + 3321344);  // 50,331,648 B
    bool use_xwg = (ws_size >= 53652992ull);

    (void)hipFuncSetAttribute(reinterpret_cast<const void*>(&k_attn<true>),
                        hipFuncAttributeMaxDynamicSharedMemorySize, 40448);
    (void)hipFuncSetAttribute(reinterpret_cast<const void*>(&k_attn<false>),
                        hipFuncAttributeMaxDynamicSharedMemorySize, 40448);

    k_prep<<<22, 256, 0, stream>>>(Wq, Wk, Wv, Wp, lw, WtT, lwT);
    if (use_xwg) {
        k_cast<<<4096, 768, 0, stream>>>(x, xwg, dsxH, dsxM, dsxL);
        k_sim_bf<<<512, 256, 0, stream>>>(dsxH, dsxM, dsxL, pi);
        k_top3x<<<1024, 256, 0, stream>>>(dsxH, dsxM, dsxL, pi, w3, i3);
        k_attn<true><<<4096, 256, 40448, stream>>>(x, xwg, WtT, lwT, bq, bk, bv, bp,
                                                   lb, w3, i3, out);
    } else {
        k_pool<<<1536, 256, 0, stream>>>(x, dsxT);
        k_sim<<<512, 256, 0, stream>>>(dsxT, pv, pi);
        k_topk<<<16, 256, 0, stream>>>(pv, pi, w3, i3);
        k_attn<false><<<4096, 256, 40448, stream>>>(x, nullptr, WtT, lwT, bq, bk, bv, bp,
                                                    lb, w3, i3, out);
    }
}

// Round 5
// 396.271 us; speedup vs baseline: 1.1698x; 1.0810x over previous
//
#include <hip/hip_runtime.h>

typedef __attribute__((ext_vector_type(8))) short  short8;
typedef __attribute__((ext_vector_type(4))) float  f32x4;
typedef __attribute__((ext_vector_type(4))) unsigned int uint4v;
typedef __attribute__((ext_vector_type(2))) unsigned int uint2v;

#define NEG_INF (-3.402823466e38f)

__device__ __forceinline__ unsigned short bfbits(float f) {
    unsigned u = __builtin_bit_cast(unsigned, f);
    u += 0x7fffu + ((u >> 16) & 1u);
    return (unsigned short)(u >> 16);
}
__device__ __forceinline__ unsigned pk_bf16(float lo, float hi) {
    return (unsigned)bfbits(lo) | ((unsigned)bfbits(hi) << 16);
}
__device__ __forceinline__ float lofp(unsigned u) {
    return __builtin_bit_cast(float, u << 16);
}
__device__ __forceinline__ float hifp(unsigned u) {
    return __builtin_bit_cast(float, u & 0xffff0000u);
}
__device__ __forceinline__ float bf2f(short x) {
    return __builtin_bit_cast(float, ((unsigned)(unsigned short)x) << 16);
}

__device__ __forceinline__ void ins3(float (&tv)[3], int (&ti)[3], float v, int ci)
{
    if (v > tv[0] || (v == tv[0] && ci < ti[0])) {
        tv[2] = tv[1]; ti[2] = ti[1];
        tv[1] = tv[0]; ti[1] = ti[0];
        tv[0] = v;     ti[0] = ci;
    } else if (v > tv[1] || (v == tv[1] && ci < ti[1])) {
        tv[2] = tv[1]; ti[2] = ti[1];
        tv[1] = v;     ti[1] = ci;
    } else if (v > tv[2] || (v == tv[2] && ci < ti[2])) {
        tv[2] = v;     ti[2] = ci;
    }
}

// -------- Kernel 1 (fallback only): maxpool fp32 ----------------------------
__global__ __launch_bounds__(256) void k_pool(const float* __restrict__ x,
                                              float* __restrict__ dsxT)
{
    int gid = blockIdx.x * 256 + threadIdx.x;
    int c = gid >> 12;
    int n = gid & 4095;
    int b = n >> 10, i = (n >> 5) & 31, j = n & 31;
    const float* p = x + (((size_t)(b * 96 + c)) << 16) + i * 2048 + j * 8;
    float4 m0 = *(const float4*)p;
    float4 m1 = *(const float4*)(p + 4);
    #pragma unroll
    for (int r = 1; r < 8; ++r) {
        float4 a0 = *(const float4*)(p + r * 256);
        float4 a1 = *(const float4*)(p + r * 256 + 4);
        m0.x = fmaxf(m0.x, a0.x); m0.y = fmaxf(m0.y, a0.y);
        m0.z = fmaxf(m0.z, a0.z); m0.w = fmaxf(m0.w, a0.w);
        m1.x = fmaxf(m1.x, a1.x); m1.y = fmaxf(m1.y, a1.y);
        m1.z = fmaxf(m1.z, a1.z); m1.w = fmaxf(m1.w, a1.w);
    }
    float m = fmaxf(fmaxf(fmaxf(m0.x, m0.y), fmaxf(m0.z, m0.w)),
                    fmaxf(fmaxf(m1.x, m1.y), fmaxf(m1.z, m1.w)));
    dsxT[c * 4096 + n] = m;
}

// -------- Kernel 0b: x -> xwg bf16 + pooled maxima as 3-way bf16 split ------
__global__ __launch_bounds__(768) void k_cast(const float* __restrict__ x,
                                              unsigned short* __restrict__ xwg,
                                              unsigned short* __restrict__ dsxH,
                                              unsigned short* __restrict__ dsxM,
                                              unsigned short* __restrict__ dsxL)
{
    int n = ((blockIdx.x & 7) << 9) | (blockIdx.x >> 3);
    int t = threadIdx.x;
    int cg = t >> 6, p = t & 63;                 // wave == one cg (8 channels)
    int b = n >> 10, i = (n >> 5) & 31, j = n & 31;
    int h = i * 8 + (p >> 3), w = j * 8 + (p & 7);
    size_t base = (((size_t)(b * 96 + 8 * cg)) << 16) + (size_t)(h * 256 + w);
    float v[8];
    #pragma unroll
    for (int jj = 0; jj < 8; ++jj) v[jj] = x[base + (((size_t)jj) << 16)];
    uint4v pk;
    #pragma unroll
    for (int jj = 0; jj < 4; ++jj) pk[jj] = pk_bf16(v[2 * jj], v[2 * jj + 1]);
    *(uint4v*)&xwg[(size_t)n * 6144 + p * 96 + 8 * cg] = pk;
    #pragma unroll
    for (int jj = 0; jj < 8; ++jj) {
        float m = v[jj];
        #pragma unroll
        for (int d = 1; d < 64; d <<= 1) m = fmaxf(m, __shfl_xor(m, d, 64));
        if (p == 0) {
            unsigned short hb = bfbits(m);
            float r1 = m - __builtin_bit_cast(float, ((unsigned)hb) << 16);
            unsigned short mb = bfbits(r1);
            float r2 = r1 - __builtin_bit_cast(float, ((unsigned)mb) << 16);
            dsxH[n * 96 + 8 * cg + jj] = hb;
            dsxM[n * 96 + 8 * cg + jj] = mb;
            dsxL[n * 96 + 8 * cg + jj] = bfbits(r2);
        }
    }
}

// -------- Kernel 2 (fallback): similarity + partial top3, fp32 VALU ---------
__global__ __launch_bounds__(256) void k_sim(const float* __restrict__ dsxT,
                                             float* __restrict__ pv,
                                             int* __restrict__ pi)
{
    __shared__ __align__(16) float qt[32 * 128];
    __shared__ __align__(16) float ct[32 * 144];
    int t = threadIdx.x;
    int qti = blockIdx.x >> 4;
    int ch  = blockIdx.x & 15;
    int ty = t >> 4, tx = t & 15;
    int qb = qti * 128;

    float tv[8][3]; int ti[8][3];
    #pragma unroll
    for (int a = 0; a < 8; ++a)
        #pragma unroll
        for (int k = 0; k < 3; ++k) { tv[a][k] = NEG_INF; ti[a][k] = 0x7fffffff; }

    #pragma unroll
    for (int pass = 0; pass < 2; ++pass) {
        int cb = ch * 256 + pass * 128;
        float acc[8][8];
        #pragma unroll
        for (int a = 0; a < 8; ++a)
            #pragma unroll
            for (int e = 0; e < 8; ++e) acc[a][e] = 0.f;

        for (int kc = 0; kc < 3; ++kc) {
            __syncthreads();
            #pragma unroll
            for (int f4 = 0; f4 < 4; ++f4) {
                int f = t + f4 * 256;
                int kk = f >> 5, cq = f & 31;
                *(float4*)&qt[kk * 128 + 4 * cq] =
                    *(const float4*)&dsxT[(kc * 32 + kk) * 4096 + qb + 4 * cq];
                *(float4*)&ct[kk * 144 + 4 * cq + 4 * (cq >> 3)] =
                    *(const float4*)&dsxT[(kc * 32 + kk) * 4096 + cb + 4 * cq];
            }
            __syncthreads();
            #pragma unroll 2
            for (int kk = 0; kk < 32; ++kk) {
                float4 q0 = *(float4*)&qt[kk * 128 + 8 * ty];
                float4 q1 = *(float4*)&qt[kk * 128 + 8 * ty + 4];
                int e0 = 8 * tx, e1 = 8 * tx + 4;
                float4 c0 = *(float4*)&ct[kk * 144 + e0 + 4 * (e0 >> 5)];
                float4 c1 = *(float4*)&ct[kk * 144 + e1 + 4 * (e1 >> 5)];
                float qv[8] = {q0.x, q0.y, q0.z, q0.w, q1.x, q1.y, q1.z, q1.w};
                float cv[8] = {c0.x, c0.y, c0.z, c0.w, c1.x, c1.y, c1.z, c1.w};
                #pragma unroll
                for (int a = 0; a < 8; ++a)
                    #pragma unroll
                    for (int e = 0; e < 8; ++e)
                        acc[a][e] = fmaf(qv[a], cv[e], acc[a][e]);
            }
        }
        #pragma unroll
        for (int e = 0; e < 8; ++e) {
            int ci = cb + 8 * tx + e;
            #pragma unroll
            for (int a = 0; a < 8; ++a) ins3(tv[a], ti[a], acc[a][e], ci);
        }
    }

    #pragma unroll
    for (int d = 1; d < 16; d <<= 1) {
        #pragma unroll
        for (int a = 0; a < 8; ++a) {
            float ov[3]; int oi[3];
            #pragma unroll
            for (int k = 0; k < 3; ++k) {
                ov[k] = __shfl_xor(tv[a][k], d, 16);
                oi[k] = __shfl_xor(ti[a][k], d, 16);
            }
            #pragma unroll
            for (int k = 0; k < 3; ++k) ins3(tv[a], ti[a], ov[k], oi[k]);
        }
    }
    if (tx == 0) {
        #pragma unroll
        for (int a = 0; a < 8; ++a) {
            int nq = qti * 128 + 8 * ty + a;
            #pragma unroll
            for (int k = 0; k < 3; ++k) {
                pv[nq * 48 + ch * 3 + k] = tv[a][k];
                pi[nq * 48 + ch * 3 + k] = ti[a][k];
            }
        }
    }
}

// -------- Kernel 2m (primary): candidate top-3 via 3-split bf16 MFMA --------
// v2: LDS-staged B subtiles (shared by 4 waves), double-buffered with one
// barrier/iter; prefetch issued before the MFMA cluster hides L2 latency.
// grid 1024 = 64 q-tiles(64 rows) x 16 cand-chunks(256); block 256 (4 waves);
// wave wv owns a-tile wv (16 q-rows). 4 blocks/CU.
__global__ __launch_bounds__(256, 4) void k_sim_bf(const unsigned short* __restrict__ dsxH,
                                                   const unsigned short* __restrict__ dsxM,
                                                   const unsigned short* __restrict__ dsxL,
                                                   int* __restrict__ pi)
{
    // 16 cand rows x {H,M,L} planes; row stride 296 shorts = 592 B = 37x16 B
    // (odd multiple of 16 -> conflict-light ds_read_b128 across 16 rows).
    __shared__ __align__(16) unsigned short Bs[2][16 * 296];   // 18944 B
    int t = threadIdx.x;
    int qti = blockIdx.x >> 4;      // 0..63
    int ch  = blockIdx.x & 15;
    int lane = t & 63, wv = t >> 6;
    int l15 = lane & 15, quad = lane >> 4;
    int cb = ch * 256;

    int qrow = qti * 64 + wv * 16 + l15;
    short8 aH[3], aM[3], aL[3];
    #pragma unroll
    for (int ks = 0; ks < 3; ++ks) {
        aH[ks] = *(const short8*)&dsxH[qrow * 96 + ks * 32 + quad * 8];
        aM[ks] = *(const short8*)&dsxM[qrow * 96 + ks * 32 + quad * 8];
        aL[ks] = *(const short8*)&dsxL[qrow * 96 + ks * 32 + quad * 8];
    }

    // staging: 576 16-B chunks per subtile (16 rows x 36); thread t covers
    // chunks {t, t+256, t+512(if t<64)}. chunk c: row=c/36, plane=(c%36)/12,
    // idx=(c%36)%12.
    int ldsoff[3], goff[3];
    const unsigned short* srcp[3];
    #pragma unroll
    for (int kc = 0; kc < 3; ++kc) {
        int c = t + kc * 256;
        int row = c / 36, w36 = c % 36;
        int plane = w36 / 12, idx = w36 % 12;
        ldsoff[kc] = row * 296 + plane * 96 + idx * 8;
        goff[kc]   = row * 96 + idx * 8;
        srcp[kc]   = (plane == 0) ? dsxH : (plane == 1) ? dsxM : dsxL;
    }
    bool third = (t < 64);

    float tv[4][3]; int ti[4][3];
    #pragma unroll
    for (int r = 0; r < 4; ++r)
        #pragma unroll
        for (int k = 0; k < 3; ++k) { tv[r][k] = NEG_INF; ti[r][k] = 0x7fffffff; }

    // prologue: stage subtile 0 -> Bs[0]
    {
        int base = cb * 96;
        uint4v v0 = *(const uint4v*)&srcp[0][base + goff[0]];
        uint4v v1 = *(const uint4v*)&srcp[1][base + goff[1]];
        *(uint4v*)&Bs[0][ldsoff[0]] = v0;
        *(uint4v*)&Bs[0][ldsoff[1]] = v1;
        if (third) {
            uint4v v2 = *(const uint4v*)&srcp[2][base + goff[2]];
            *(uint4v*)&Bs[0][ldsoff[2]] = v2;
        }
    }
    __syncthreads();

    for (int st = 0; st < 16; ++st) {
        int cur = st & 1;
        uint4v p0, p1, p2;
        if (st < 15) {                       // prefetch next subtile early
            int base = (cb + (st + 1) * 16) * 96;
            p0 = *(const uint4v*)&srcp[0][base + goff[0]];
            p1 = *(const uint4v*)&srcp[1][base + goff[1]];
            if (third) p2 = *(const uint4v*)&srcp[2][base + goff[2]];
        }
        f32x4 c = {0.f, 0.f, 0.f, 0.f};
        f32x4 c2 = {0.f, 0.f, 0.f, 0.f};
        #pragma unroll
        for (int ks = 0; ks < 3; ++ks) {
            int bo = l15 * 296 + ks * 32 + quad * 8;
            short8 bH = *(const short8*)&Bs[cur][bo];
            short8 bM = *(const short8*)&Bs[cur][bo + 96];
            short8 bL = *(const short8*)&Bs[cur][bo + 192];
            c  = __builtin_amdgcn_mfma_f32_16x16x32_bf16(aH[ks], bH, c,  0, 0, 0);
            c2 = __builtin_amdgcn_mfma_f32_16x16x32_bf16(aH[ks], bM, c2, 0, 0, 0);
            c2 = __builtin_amdgcn_mfma_f32_16x16x32_bf16(aM[ks], bH, c2, 0, 0, 0);
            c2 = __builtin_amdgcn_mfma_f32_16x16x32_bf16(aM[ks], bM, c2, 0, 0, 0);
            c2 = __builtin_amdgcn_mfma_f32_16x16x32_bf16(aH[ks], bL, c2, 0, 0, 0);
            c2 = __builtin_amdgcn_mfma_f32_16x16x32_bf16(aL[ks], bH, c2, 0, 0, 0);
        }
        #pragma unroll
        for (int r = 0; r < 4; ++r)
            ins3(tv[r], ti[r], c[r] + c2[r], cb + st * 16 + l15);
        // write prefetched subtile into the other buffer (no wave reads it
        // now: the end-of-previous-iter barrier retired all its readers)
        if (st < 15) {
            *(uint4v*)&Bs[cur ^ 1][ldsoff[0]] = p0;
            *(uint4v*)&Bs[cur ^ 1][ldsoff[1]] = p1;
            if (third) *(uint4v*)&Bs[cur ^ 1][ldsoff[2]] = p2;
        }
        __syncthreads();
    }

    // merge across the 16 l15-lanes (same quad -> same 4 q-rows)
    #pragma unroll
    for (int d = 1; d < 16; d <<= 1) {
        #pragma unroll
        for (int r = 0; r < 4; ++r) {
            float ov[3]; int oi[3];
            #pragma unroll
            for (int k = 0; k < 3; ++k) {
                ov[k] = __shfl_xor(tv[r][k], d, 16);
                oi[k] = __shfl_xor(ti[r][k], d, 16);
            }
            #pragma unroll
            for (int k = 0; k < 3; ++k) ins3(tv[r], ti[r], ov[k], oi[k]);
        }
    }
    if (l15 == 0) {
        #pragma unroll
        for (int r = 0; r < 4; ++r) {
            int nq = qti * 64 + wv * 16 + quad * 4 + r;
            #pragma unroll
            for (int k = 0; k < 3; ++k)
                pi[nq * 48 + ch * 3 + k] = ti[r][k];
        }
    }
}

// -------- Kernel 2x (primary): exact fp32 rescore of 48 candidates ----------
__global__ __launch_bounds__(256) void k_top3x(const unsigned short* __restrict__ dsxH,
                                               const unsigned short* __restrict__ dsxM,
                                               const unsigned short* __restrict__ dsxL,
                                               const int* __restrict__ pi,
                                               float* __restrict__ w3,
                                               int* __restrict__ i3)
{
    int t = threadIdx.x;
    int lane = t & 63, wv = t >> 6;
    int n = blockIdx.x * 4 + wv;
    int cand = (lane < 48) ? pi[n * 48 + lane] : 0;
    float s = 0.f;
    #pragma unroll
    for (int ck = 0; ck < 12; ++ck) {
        short8 qh = *(const short8*)&dsxH[n * 96 + ck * 8];
        short8 qm = *(const short8*)&dsxM[n * 96 + ck * 8];
        short8 ql = *(const short8*)&dsxL[n * 96 + ck * 8];
        short8 kh = *(const short8*)&dsxH[cand * 96 + ck * 8];
        short8 km = *(const short8*)&dsxM[cand * 96 + ck * 8];
        short8 kl = *(const short8*)&dsxL[cand * 96 + ck * 8];
        #pragma unroll
        for (int e = 0; e < 8; ++e) {
            float qv = (bf2f(qh[e]) + bf2f(qm[e])) + bf2f(ql[e]);
            float kv = (bf2f(kh[e]) + bf2f(km[e])) + bf2f(kl[e]);
            s = fmaf(qv, kv, s);
        }
    }
    float tv[3] = {NEG_INF, NEG_INF, NEG_INF};
    int   ti[3] = {0x7fffffff, 0x7fffffff, 0x7fffffff};
    if (lane < 48) { tv[0] = s; ti[0] = cand; }
    #pragma unroll
    for (int d = 1; d < 64; d <<= 1) {
        float ov[3]; int oi[3];
        #pragma unroll
        for (int k = 0; k < 3; ++k) {
            ov[k] = __shfl_xor(tv[k], d, 64);
            oi[k] = __shfl_xor(ti[k], d, 64);
        }
        #pragma unroll
        for (int k = 0; k < 3; ++k) ins3(tv, ti, ov[k], oi[k]);
    }
    if (lane == 0) {
        float e1 = expf(tv[1] - tv[0]);
        float e2 = expf(tv[2] - tv[0]);
        float inv = 1.f / (1.f + e1 + e2);
        w3[n * 3 + 0] = inv;
        w3[n * 3 + 1] = e1 * inv;
        w3[n * 3 + 2] = e2 * inv;
        i3[n * 3 + 0] = ti[0];
        i3[n * 3 + 1] = ti[1];
        i3[n * 3 + 2] = ti[2];
    }
}

// ---------------- Kernel 2b (fallback): final top3 merge + softmax ----------
__global__ __launch_bounds__(256) void k_topk(const float* __restrict__ pv,
                                              const int* __restrict__ pi,
                                              float* __restrict__ w3,
                                              int* __restrict__ i3)
{
    int n = blockIdx.x * 256 + threadIdx.x;
    float bv[3] = {NEG_INF, NEG_INF, NEG_INF};
    int   bi[3] = {0x7fffffff, 0x7fffffff, 0x7fffffff};
    for (int e = 0; e < 48; ++e)
        ins3(bv, bi, pv[n * 48 + e], pi[n * 48 + e]);
    float e1 = expf(bv[1] - bv[0]);
    float e2 = expf(bv[2] - bv[0]);
    float inv = 1.f / (1.f + e1 + e2);
    w3[n * 3 + 0] = inv;
    w3[n * 3 + 1] = e1 * inv;
    w3[n * 3 + 2] = e2 * inv;
    i3[n * 3 + 0] = bi[0];
    i3[n * 3 + 1] = bi[1];
    i3[n * 3 + 2] = bi[2];
}

// -------- Kernel 0a: weights -> WtT[4][96co][96ci] bf16 ; lwT[9][96] fp32 ---
__global__ __launch_bounds__(256) void k_prep(const float* __restrict__ Wq,
                                              const float* __restrict__ Wk,
                                              const float* __restrict__ Wv,
                                              const float* __restrict__ Wp,
                                              const float* __restrict__ lw,
                                              unsigned short* __restrict__ WtT,
                                              float* __restrict__ lwT)
{
    int g = blockIdx.x * 256 + threadIdx.x;
    if (g < 4608) {
        int w  = g / 1152;
        int co = (g % 1152) / 12;
        int cg = g % 12;
        const float* src = (w == 0) ? Wq : (w == 1) ? Wk : (w == 2) ? Wv : Wp;
        unsigned short* dst = WtT + w * 9216 + co * 96 + 8 * cg;
        #pragma unroll
        for (int j = 0; j < 8; ++j) dst[j] = bfbits(src[(8 * cg + j) * 96 + co]);
    } else if (g < 5472) {
        int i2 = g - 4608;
        int tap = i2 / 96, c = i2 % 96;
        lwT[tap * 96 + c] = lw[c * 9 + tap];
    }
}

// ----------------------- Kernel 3: fused MFMA window attention --------------
__device__ __forceinline__ size_t win_off(int m)
{
    return (((size_t)(m >> 10) * 96) << 16) +
           (size_t)(((m >> 5) & 31) * 2048 + (m & 31) * 8);
}

__device__ __forceinline__ void gemm_g(const short8* af,
                                       const unsigned short* __restrict__ Wt,
                                       int l15, int quad, f32x4* acc)
{
    __builtin_amdgcn_s_setprio(1);
    #pragma unroll
    for (int nt = 0; nt < 6; ++nt) {
        f32x4 c = {0.f, 0.f, 0.f, 0.f};
        #pragma unroll
        for (int ks = 0; ks < 3; ++ks) {
            short8 bf = *(const short8*)&Wt[(nt * 16 + l15) * 96 + ks * 32 + quad * 8];
            c = __builtin_amdgcn_mfma_f32_16x16x32_bf16(af[ks], bf, c, 0, 0, 0);
        }
        acc[nt] = c;
    }
    __builtin_amdgcn_s_setprio(0);
}

template<bool XWG>
__global__ __attribute__((amdgpu_waves_per_eu(4, 4)))
__launch_bounds__(256) void k_attn(
    const float* __restrict__ x,
    const unsigned short* __restrict__ xwg,
    const unsigned short* __restrict__ WtT,
    const float* __restrict__ lwT,
    const float* __restrict__ bq, const float* __restrict__ bk,
    const float* __restrict__ bv, const float* __restrict__ bp,
    const float* __restrict__ lb,
    const float* __restrict__ w3, const int* __restrict__ i3,
    float* __restrict__ out)
{
    extern __shared__ __align__(16) unsigned short sm[];
    unsigned short* buf1 = sm;            // 6656 shorts
    unsigned short* buf2 = sm + 6656;     // 6656 shorts
    unsigned short* Vt   = sm + 13312;    // 6912 shorts

    int t = threadIdx.x;
    int n = ((blockIdx.x & 7) << 9) | (blockIdx.x >> 3);
    int lane = t & 63, mt = t >> 6;
    int l15 = lane & 15, quad = lane >> 4;

    float wk0 = w3[n * 3 + 0], wk1 = w3[n * 3 + 1], wk2 = w3[n * 3 + 2];
    int   m0  = i3[n * 3 + 0], m1 = i3[n * 3 + 1], m2 = i3[n * 3 + 2];

    if (XWG) {
        #pragma unroll
        for (int it = 0; it < 3; ++it) {
            int g = it * 256 + t;
            int p = g / 12, cg = g % 12;
            int o = p * 96 + 8 * cg;
            uint4v sv = *(const uint4v*)&xwg[(size_t)n * 6144 + o];
            *(uint4v*)&buf1[p * 104 + 8 * cg] = sv;
            uint4v a0 = *(const uint4v*)&xwg[(size_t)m0 * 6144 + o];
            uint4v a1 = *(const uint4v*)&xwg[(size_t)m1 * 6144 + o];
            uint4v a2 = *(const uint4v*)&xwg[(size_t)m2 * 6144 + o];
            uint4v rs;
            #pragma unroll
            for (int e = 0; e < 4; ++e) {
                float lo = wk0 * lofp(a0[e]) + wk1 * lofp(a1[e]) + wk2 * lofp(a2[e]);
                float hi = wk0 * hifp(a0[e]) + wk1 * hifp(a1[e]) + wk2 * hifp(a2[e]);
                rs[e] = pk_bf16(lo, hi);
            }
            *(uint4v*)&buf2[p * 104 + 8 * cg] = rs;
        }
    } else {
        size_t so = win_off(n), o0 = win_off(m0), o1 = win_off(m1), o2 = win_off(m2);
        #pragma unroll
        for (int it = 0; it < 3; ++it) {
            int g = it * 256 + t;
            int p = g / 12, cg = g % 12;
            size_t po = (size_t)((p >> 3) * 256 + (p & 7));
            uint4v ra, rb;
            #pragma unroll
            for (int jj = 0; jj < 4; ++jj) {
                size_t clo = (((size_t)(8 * cg + 2 * jj)) << 16) + po;
                size_t chi = clo + ((size_t)1 << 16);
                ra[jj] = pk_bf16(x[so + clo], x[so + chi]);
                float blo = wk0 * x[o0 + clo] + wk1 * x[o1 + clo] + wk2 * x[o2 + clo];
                float bhi = wk0 * x[o0 + chi] + wk1 * x[o1 + chi] + wk2 * x[o2 + chi];
                rb[jj] = pk_bf16(blo, bhi);
            }
            *(uint4v*)&buf1[p * 104 + 8 * cg] = ra;
            *(uint4v*)&buf2[p * 104 + 8 * cg] = rb;
        }
    }
    __syncthreads();

    short8 af_a[3], af_b[3];
    int arow = (mt * 16 + l15) * 104;
    #pragma unroll
    for (int ks = 0; ks < 3; ++ks) {
        af_a[ks] = *(const short8*)&buf1[arow + ks * 32 + quad * 8];
        af_b[ks] = *(const short8*)&buf2[arow + ks * 32 + quad * 8];
    }
    unsigned Lp[12];
    {
        int rowp = mt * 16 + l15;
        int c0 = 24 * quad;
        int rr0 = rowp >> 3, ss0 = rowp & 7;
        float lac[24];
        #pragma unroll
        for (int q4 = 0; q4 < 6; ++q4) {
            float4 bb = *(const float4*)&lb[c0 + 4 * q4];
            lac[4 * q4] = bb.x; lac[4 * q4 + 1] = bb.y;
            lac[4 * q4 + 2] = bb.z; lac[4 * q4 + 3] = bb.w;
        }
        #pragma unroll
        for (int dr = -1; dr <= 1; ++dr) {
            int rr = rr0 + dr;
            if ((unsigned)rr >= 8u) continue;
            #pragma unroll
            for (int dss = -1; dss <= 1; ++dss) {
                int ss = ss0 + dss;
                if ((unsigned)ss >= 8u) continue;
                int pp = rr * 8 + ss;
                int tap = (dr + 1) * 3 + (dss + 1);
                const uint4v* ap = (const uint4v*)&buf1[pp * 104 + c0];
                uint4v av0 = ap[0], av1 = ap[1], av2 = ap[2];
                float wf[24];
                #pragma unroll
                for (int q4 = 0; q4 < 6; ++q4) {
                    float4 ww = *(const float4*)&lwT[tap * 96 + c0 + 4 * q4];
                    wf[4 * q4] = ww.x; wf[4 * q4 + 1] = ww.y;
                    wf[4 * q4 + 2] = ww.z; wf[4 * q4 + 3] = ww.w;
                }
                #pragma unroll
                for (int u = 0; u < 12; ++u) {
                    unsigned uu = (u < 4) ? av0[u] : (u < 8) ? av1[u - 4] : av2[u - 8];
                    lac[2 * u]     = fmaf(wf[2 * u],     lofp(uu), lac[2 * u]);
                    lac[2 * u + 1] = fmaf(wf[2 * u + 1], hifp(uu), lac[2 * u + 1]);
                }
            }
        }
        #pragma unroll
        for (int u = 0; u < 12; ++u) Lp[u] = pk_bf16(lac[2 * u], lac[2 * u + 1]);
    }
    __syncthreads();

    {
        f32x4 qa[6];
        gemm_g(af_a, WtT, l15, quad, qa);
        #pragma unroll
        for (int nt = 0; nt < 6; ++nt) {
            int col = nt * 16 + l15;
            float bb = bq[col];
            #pragma unroll
            for (int r = 0; r < 4; ++r)
                buf1[(mt * 16 + quad * 4 + r) * 104 + col] = bfbits(qa[nt][r] + bb);
        }
    }
    __builtin_amdgcn_sched_barrier(0);
    {
        f32x4 ka[6];
        gemm_g(af_b, WtT + 9216, l15, quad, ka);
        #pragma unroll
        for (int nt = 0; nt < 6; ++nt) {
            int col = nt * 16 + l15;
            float bb = bk[col];
            #pragma unroll
            for (int r = 0; r < 4; ++r)
                buf2[(mt * 16 + quad * 4 + r) * 104 + col] = bfbits(ka[nt][r] + bb);
        }
    }
    __builtin_amdgcn_sched_barrier(0);
    {
        f32x4 va[6];
        gemm_g(af_b, WtT + 18432, l15, quad, va);
        #pragma unroll
        for (int nt = 0; nt < 6; ++nt) {
            float bb = bv[nt * 16 + l15];
            uint2v pk;
            pk[0] = pk_bf16(va[nt][0] + bb, va[nt][1] + bb);
            pk[1] = pk_bf16(va[nt][2] + bb, va[nt][3] + bb);
            *(uint2v*)&Vt[(nt * 16 + l15) * 72 + mt * 16 + quad * 4] = pk;
        }
    }
    __syncthreads();

    float pr[4][4], inv4[4];
    {
        short8 qf[3];
        #pragma unroll
        for (int ks = 0; ks < 3; ++ks)
            qf[ks] = *(const short8*)&buf1[arow + ks * 32 + quad * 8];
        f32x4 sa[4];
        __builtin_amdgcn_s_setprio(1);
        #pragma unroll
        for (int nt = 0; nt < 4; ++nt) {
            f32x4 c = {0.f, 0.f, 0.f, 0.f};
            #pragma unroll
            for (int ks = 0; ks < 3; ++ks) {
                short8 bf = *(const short8*)&buf2[(nt * 16 + l15) * 104 + ks * 32 + quad * 8];
                c = __builtin_amdgcn_mfma_f32_16x16x32_bf16(qf[ks], bf, c, 0, 0, 0);
            }
            sa[nt] = c;
        }
        __builtin_amdgcn_s_setprio(0);
        const float scale = 0.10206207261596575f;
        #pragma unroll
        for (int r = 0; r < 4; ++r) {
            float mx = fmaxf(fmaxf(sa[0][r], sa[1][r]), fmaxf(sa[2][r], sa[3][r]));
            #pragma unroll
            for (int d = 1; d < 16; d <<= 1) mx = fmaxf(mx, __shfl_xor(mx, d, 16));
            float sum = 0.f;
            #pragma unroll
            for (int nt = 0; nt < 4; ++nt) {
                float e = __expf((sa[nt][r] - mx) * scale);
                pr[r][nt] = e; sum += e;
            }
            #pragma unroll
            for (int d = 1; d < 16; d <<= 1) sum += __shfl_xor(sum, d, 16);
            inv4[r] = 1.f / sum;
        }
    }
    __syncthreads();

    #pragma unroll
    for (int r = 0; r < 4; ++r) {
        #pragma unroll
        for (int nt = 0; nt < 4; ++nt)
            buf1[(mt * 16 + quad * 4 + r) * 104 + nt * 16 + l15] =
                bfbits(pr[r][nt] * inv4[r]);
    }
    {
        uint4v* lp = (uint4v*)&buf2[arow + 24 * quad];
        uint4v l0 = {Lp[0], Lp[1], Lp[2], Lp[3]};
        uint4v l1 = {Lp[4], Lp[5], Lp[6], Lp[7]};
        uint4v l2 = {Lp[8], Lp[9], Lp[10], Lp[11]};
        lp[0] = l0; lp[1] = l1; lp[2] = l2;
    }

    {
        short8 sf[2];
        sf[0] = *(const short8*)&buf1[arow + quad * 8];
        sf[1] = *(const short8*)&buf1[arow + 32 + quad * 8];
        f32x4 oa[6];
        __builtin_amdgcn_s_setprio(1);
        #pragma unroll
        for (int nt = 0; nt < 6; ++nt) {
            f32x4 c = {0.f, 0.f, 0.f, 0.f};
            #pragma unroll
            for (int ks = 0; ks < 2; ++ks) {
                short8 bf = *(const short8*)&Vt[(nt * 16 + l15) * 72 + ks * 32 + quad * 8];
                c = __builtin_amdgcn_mfma_f32_16x16x32_bf16(sf[ks], bf, c, 0, 0, 0);
            }
            oa[nt] = c;
        }
        __builtin_amdgcn_s_setprio(0);
        #pragma unroll
        for (int nt = 0; nt < 6; ++nt)
            #pragma unroll
            for (int r = 0; r < 4; ++r)
                buf1[(mt * 16 + quad * 4 + r) * 104 + nt * 16 + l15] = bfbits(oa[nt][r]);
    }

    {
        short8 of[3], lf[3];
        #pragma unroll
        for (int ks = 0; ks < 3; ++ks) {
            of[ks] = *(const short8*)&buf1[arow + ks * 32 + quad * 8];
            lf[ks] = *(const short8*)&buf2[arow + ks * 32 + quad * 8];
        }
        const unsigned short* Wp_ = WtT + 27648;
        int b = n >> 10, ii = (n >> 5) & 31, jj = n & 31;
        size_t pbase = (size_t)(ii * 2048 + jj * 8 + mt * 512 +
                                (quad >> 1) * 256 + (quad & 1) * 4);
        __builtin_amdgcn_s_setprio(1);
        #pragma unroll
        for (int nt = 0; nt < 6; ++nt) {
            f32x4 c = {0.f, 0.f, 0.f, 0.f};
            #pragma unroll
            for (int ks = 0; ks < 3; ++ks) {
                short8 bf = *(const short8*)&Wp_[(nt * 16 + l15) * 96 + ks * 32 + quad * 8];
                c = __builtin_amdgcn_mfma_f32_16x16x32_bf16(of[ks], bf, c, 0, 0, 0);
                c = __builtin_amdgcn_mfma_f32_16x16x32_bf16(lf[ks], bf, c, 0, 0, 0);
            }
            int co = nt * 16 + l15;
            float bb = bp[co];
            float4 st;
            st.x = c[0] + bb; st.y = c[1] + bb; st.z = c[2] + bb; st.w = c[3] + bb;
            *(float4*)&out[(((size_t)(b * 96 + co)) << 16) + pbase] = st;
        }
        __builtin_amdgcn_s_setprio(0);
    }
}

// ---------------------------------------------------------------------------
extern "C" void kernel_launch(void* const* d_in, const int* in_sizes, int n_in,
                              void* d_out, int out_size, void* d_ws, size_t ws_size,
                              hipStream_t stream)
{
    (void)in_sizes; (void)n_in; (void)out_size;
    const float* x  = (const float*)d_in[0];
    const float* Wq = (const float*)d_in[1];
    const float* bq = (const float*)d_in[2];
    const float* Wk = (const float*)d_in[3];
    const float* bk = (const float*)d_in[4];
    const float* Wv = (const float*)d_in[5];
    const float* bv = (const float*)d_in[6];
    const float* Wp = (const float*)d_in[7];
    const float* bp = (const float*)d_in[8];
    const float* lw = (const float*)d_in[9];
    const float* lb = (const float*)d_in[10];
    float* out = (float*)d_out;

    char* ws = (char*)d_ws;
    float* dsxT = (float*)ws;                               // 1,572,864 B (fallback)
    unsigned short* dsxH = (unsigned short*)ws;             //   786,432 B (primary)
    unsigned short* dsxM = (unsigned short*)(ws + 786432);  //   786,432 B (primary)
    unsigned short* dsxL = (unsigned short*)(ws + 1572864); //   786,432 B (primary; aliases pv)
    float* pv   = (float*)(ws + 1572864);                   //   786,432 B (fallback)
    int*   pi   = (int*)  (ws + 2359296);                   //   786,432 B
    float* w3   = (float*)(ws + 3145728);                   //    49,152 B
    int*   i3   = (int*)  (ws + 3194880);                   //    49,152 B
    unsigned short* WtT = (unsigned short*)(ws + 3244032);  //    73,728 B
    float* lwT  = (float*)(ws + 3317760);                   //     3,456 B
    unsigned short* xwg = (unsigned short*)(ws + 3321344);  // 50,331,648 B
    bool use_xwg = (ws_size >= 53652992ull);

    (void)hipFuncSetAttribute(reinterpret_cast<const void*>(&k_attn<true>),
                        hipFuncAttributeMaxDynamicSharedMemorySize, 40448);
    (void)hipFuncSetAttribute(reinterpret_cast<const void*>(&k_attn<false>),
                        hipFuncAttributeMaxDynamicSharedMemorySize, 40448);

    k_prep<<<22, 256, 0, stream>>>(Wq, Wk, Wv, Wp, lw, WtT, lwT);
    if (use_xwg) {
        k_cast<<<4096, 768, 0, stream>>>(x, xwg, dsxH, dsxM, dsxL);
        k_sim_bf<<<1024, 256, 0, stream>>>(dsxH, dsxM, dsxL, pi);
        k_top3x<<<1024, 256, 0, stream>>>(dsxH, dsxM, dsxL, pi, w3, i3);
        k_attn<true><<<4096, 256, 40448, stream>>>(x, xwg, WtT, lwT, bq, bk, bv, bp,
                                                   lb, w3, i3, out);
    } else {
        k_pool<<<1536, 256, 0, stream>>>(x, dsxT);
        k_sim<<<512, 256, 0, stream>>>(dsxT, pv, pi);
        k_topk<<<16, 256, 0, stream>>>(pv, pi, w3, i3);
        k_attn<false><<<4096, 256, 40448, stream>>>(x, nullptr, WtT, lwT, bq, bk, bv, bp,
                                                    lb, w3, i3, out);
    }
}